// Round 12
// baseline (711.483 us; speedup 1.0000x reference)
//
#include <hip/hip_runtime.h>
#include <cstdint>
#include <cstddef>

#define BATCH       65536
#define LDSW        36          // padded LDS row stride for tiny-kernel matrices
#define NCHEB       16          // Chebyshev terms on [CALPHA, CBETA] (validated r7/r8)
#define CALPHA      0.28f
#define CBETA       4.6f
#define NS_ITERS    4
#define EXP_TERMS   8
#define MAIN_BLOCKS 3072        // kD grid (unchanged r9 path)
#define GRID_BC     8192        // kB/kC: LDS-free; 8 waves/SIMD available, VGPR allows 6

// ws float offsets
#define OFF_MEAN0   0
#define OFF_INVS0   1024
#define OFF_S0      2048
#define OFF_LOGAVG  3072
#define OFF_INVS    4096
#define OFF_SSQRT   5120
#define OFF_VAR     6144
#define OFF_P       6145
#define OFF_CHEB    6152

typedef float (*LdsMat)[LDSW];
typedef __attribute__((ext_vector_type(8)))  short short8;
typedef __attribute__((ext_vector_type(2)))  float f32x2;
typedef __attribute__((ext_vector_type(4)))  float f32x4;
typedef __attribute__((ext_vector_type(16))) float f32x16;
typedef unsigned short u16t;
typedef unsigned int   u32t;

#define MFMA16(a, b, c) __builtin_amdgcn_mfma_f32_16x16x32_bf16((a), (b), (c), 0, 0, 0)
#define MFMA32(a, b, c) __builtin_amdgcn_mfma_f32_32x32x16_bf16((a), (b), (c), 0, 0, 0)

// ---------------- packed-f32 helpers (v_pk_* : 2 floats per issue slot) ----------------
union V16 { f32x16 v; f32x2 p[8]; };
// r = k*x + y (elementwise)
__device__ __forceinline__ f32x16 pk_axpy(float k, const f32x16& x, const f32x16& y) {
  V16 X, Y, R;
  X.v = x; Y.v = y;
  f32x2 kk; kk[0] = k; kk[1] = k;
#pragma unroll
  for (int d = 0; d < 8; ++d) R.p[d] = kk * X.p[d] + Y.p[d];
  return R.v;
}
__device__ __forceinline__ f32x16 pk_neg(const f32x16& x) {
  V16 X, R;
  X.v = x;
  f32x2 m; m[0] = -1.f; m[1] = -1.f;
#pragma unroll
  for (int d = 0; d < 8; ++d) R.p[d] = X.p[d] * m;
  return R.v;
}
__device__ __forceinline__ f32x16 pk_add2(const f32x16& x) {   // x + x
  V16 X, R;
  X.v = x;
#pragma unroll
  for (int d = 0; d < 8; ++d) R.p[d] = X.p[d] + X.p[d];
  return R.v;
}

// ---------------- bf16 pack / split helpers (perm-based, proven r4-r11) ----------------
__device__ __forceinline__ u32t pack2_rn(float a, float b) {
  u32t ua = __float_as_uint(a) + 0x8000u;
  u32t ub = __float_as_uint(b) + 0x8000u;
  return __builtin_amdgcn_perm(ub, ua, 0x07060302u);
}
__device__ __forceinline__ void split2(float a, float b, u32t& hw, u32t& lw) {
  u32t ua = __float_as_uint(a) + 0x8000u;
  u32t ub = __float_as_uint(b) + 0x8000u;
  hw = __builtin_amdgcn_perm(ub, ua, 0x07060302u);
  float ra = a - __uint_as_float(ua & 0xFFFF0000u);
  float rb = b - __uint_as_float(ub & 0xFFFF0000u);
  lw = __builtin_amdgcn_perm(__float_as_uint(rb), __float_as_uint(ra), 0x07060302u);
}
__device__ __forceinline__ void split8regs(float4 a, float4 b, float mul, short8& hi, short8& lo) {
  u32t h0, l0, h1, l1, h2, l2, h3, l3;
  split2(a.x * mul, a.y * mul, h0, l0);
  split2(a.z * mul, a.w * mul, h1, l1);
  split2(b.x * mul, b.y * mul, h2, l2);
  split2(b.z * mul, b.w * mul, h3, l3);
  union { uint4 u; short8 s; } uh, ul;
  uh.u.x = h0; uh.u.y = h1; uh.u.z = h2; uh.u.w = h3;
  ul.u.x = l0; ul.u.y = l1; ul.u.z = l2; ul.u.w = l3;
  hi = uh.s; lo = ul.s;
}
__device__ __forceinline__ void splitf(float a, u16t& h, u16t& l) {
  unsigned u  = __float_as_uint(a);
  unsigned uh = (u + 0x8000u) & 0xFFFF0000u;
  float    r  = a - __uint_as_float(uh);
  unsigned ul = __float_as_uint(r) + 0x8000u;
  h = (u16t)(uh >> 16);
  l = (u16t)(ul >> 16);
}

// ---------------- 32x32 register-exchange helpers (r11-verified wiring) ----------------
// C-layout (32x32): lane = 32q + n holds D[row=(rr&3)+8(rr>>2)+4q][col=n], rr=0..15.
// B-frag (32x32x16, K-tile t): lane needs B[k=16t+8q+j][n], j=0..7.
// v_permlane32_swap(a,b): ret[0] = {a.row0 | b.row0->hi}, ret[1] = {a.row1->lo | b.row1}.
__device__ __forceinline__ void cmaj_to_bfrag(const f32x16& v, short8& f0, short8& f1) {
  u32t w[8];
#pragma unroll
  for (int d = 0; d < 8; ++d) w[d] = pack2_rn(v[2 * d], v[2 * d + 1]);
  auto r02 = __builtin_amdgcn_permlane32_swap(w[0], w[2], false, false);
  auto r13 = __builtin_amdgcn_permlane32_swap(w[1], w[3], false, false);
  auto r46 = __builtin_amdgcn_permlane32_swap(w[4], w[6], false, false);
  auto r57 = __builtin_amdgcn_permlane32_swap(w[5], w[7], false, false);
  union { uint4 u; short8 s; } A, B;
  A.u.x = r02[0]; A.u.y = r13[0]; A.u.z = r02[1]; A.u.w = r13[1];
  B.u.x = r46[0]; B.u.y = r57[0]; B.u.z = r46[1]; B.u.w = r57[1];
  f0 = A.s; f1 = B.s;
}
__device__ __forceinline__ void cmaj_to_bfrag_split(const f32x16& v,
    short8& f0h, short8& f1h, short8& f0l, short8& f1l) {
  u32t wh[8], wl[8];
#pragma unroll
  for (int d = 0; d < 8; ++d) split2(v[2 * d], v[2 * d + 1], wh[d], wl[d]);
  {
    auto r02 = __builtin_amdgcn_permlane32_swap(wh[0], wh[2], false, false);
    auto r13 = __builtin_amdgcn_permlane32_swap(wh[1], wh[3], false, false);
    auto r46 = __builtin_amdgcn_permlane32_swap(wh[4], wh[6], false, false);
    auto r57 = __builtin_amdgcn_permlane32_swap(wh[5], wh[7], false, false);
    union { uint4 u; short8 s; } A, B;
    A.u.x = r02[0]; A.u.y = r13[0]; A.u.z = r02[1]; A.u.w = r13[1];
    B.u.x = r46[0]; B.u.y = r57[0]; B.u.z = r46[1]; B.u.w = r57[1];
    f0h = A.s; f1h = B.s;
  }
  {
    auto r02 = __builtin_amdgcn_permlane32_swap(wl[0], wl[2], false, false);
    auto r13 = __builtin_amdgcn_permlane32_swap(wl[1], wl[3], false, false);
    auto r46 = __builtin_amdgcn_permlane32_swap(wl[4], wl[6], false, false);
    auto r57 = __builtin_amdgcn_permlane32_swap(wl[5], wl[7], false, false);
    union { uint4 u; short8 s; } A, B;
    A.u.x = r02[0]; A.u.y = r13[0]; A.u.z = r02[1]; A.u.w = r13[1];
    B.u.x = r46[0]; B.u.y = r57[0]; B.u.z = r46[1]; B.u.w = r57[1];
    f0l = A.s; f1l = B.s;
  }
}
// Cold: load symmetric 32x32 f32 -> A/B frags (row n, k = 16t+8q+j)
__device__ __forceinline__ void load_sym_frags32(const float* base, int n, int q,
                                                 short8* Fh, short8* Fl) {
#pragma unroll
  for (int t = 0; t < 2; ++t) {
    const float* sp = base + n * 32 + 16 * t + 8 * q;
    short8 hh, ll;
#pragma unroll
    for (int j = 0; j < 8; ++j) {
      u16t h, l;
      splitf(sp[j], h, l);
      hh[j] = (short)h;
      ll[j] = (short)l;
    }
    Fh[t] = hh;
    Fl[t] = ll;
  }
}

// ---------------- register-only whiten + forward-Chebyshev log (32x32 MFMA) ----------------
// L = cheb_log( GSC*(S x S) - MSH*I ), all operand exchange via permlane32_swap; zero LDS.
template <bool ACCUM>
__device__ __forceinline__ void whiten_cheb32(
    const float* __restrict__ xb, const short8* S_h, const short8* S_l,
    const float* __restrict__ cof, int q, int n, f32x16& L) {
  f32x16 z16;
#pragma unroll
  for (int rr = 0; rr < 16; ++rr) z16[rr] = 0.f;
  // 1. X A-frags direct from global (X symmetric)
  short8 Xh[2], Xl[2];
#pragma unroll
  for (int t = 0; t < 2; ++t) {
    const float* p = xb + n * 32 + 16 * t + 8 * q;
    float4 a = *reinterpret_cast<const float4*>(p);
    float4 b = *reinterpret_cast<const float4*>(p + 4);
    split8regs(a, b, 1.f, Xh[t], Xl[t]);
  }
  // 2. V2 = X * S
  f32x16 v2 = z16;
#pragma unroll
  for (int t = 0; t < 2; ++t) {
    v2 = MFMA32(Xl[t], S_h[t], v2);
    v2 = MFMA32(Xh[t], S_l[t], v2);
    v2 = MFMA32(Xh[t], S_h[t], v2);
  }
  // 3. V2 B-frags (split) in registers
  short8 Vh[2], Vl[2];
  cmaj_to_bfrag_split(v2, Vh[0], Vh[1], Vl[0], Vl[1]);
  // 4. Y = S * V2
  f32x16 y = z16;
#pragma unroll
  for (int t = 0; t < 2; ++t) {
    y = MFMA32(S_l[t], Vh[t], y);
    y = MFMA32(S_h[t], Vl[t], y);
    y = MFMA32(S_h[t], Vh[t], y);
  }
  // 5. T1 = GSC*Y - MSH*I ; init L, nTm2
  const float GSC = 2.f / (CBETA - CALPHA);
  const float MSH = (CALPHA + CBETA) / (CBETA - CALPHA);
  const float c0 = cof[0], c1 = cof[1];
  f32x16 accB, nTm2;
#pragma unroll
  for (int rr = 0; rr < 16; ++rr) {
    int row = (rr & 3) + 8 * (rr >> 2) + 4 * q;
    float dgf = (row == n) ? 1.f : 0.f;
    float t1 = fmaf(y[rr], GSC, -MSH * dgf);
    accB[rr] = t1;
    nTm2[rr] = -dgf;
    float base = ACCUM ? L[rr] : 0.f;
    L[rr] = fmaf(c1, t1, fmaf(c0, dgf, base));
  }
  // A-frags of 2*Ytilde (symmetric) split
  f32x16 y2 = pk_add2(accB);
  short8 Yh[2], Yl[2];
  cmaj_to_bfrag_split(y2, Yh[0], Yh[1], Yl[0], Yl[1]);
  // 6. T_k = MFMA(2Yt, bf16(T_{k-1}), -T_{k-2}); L += c_k T_k   (register-only, packed VALU)
#pragma unroll
  for (int k = 2; k < NCHEB; ++k) {
    short8 B0, B1;
    cmaj_to_bfrag(accB, B0, B1);
    f32x16 acc = nTm2;
    acc = MFMA32(Yl[0], B0, acc);
    acc = MFMA32(Yh[0], B0, acc);
    acc = MFMA32(Yl[1], B1, acc);
    acc = MFMA32(Yh[1], B1, acc);
    L    = pk_axpy(cof[k], acc, L);
    nTm2 = pk_neg(accB);
    accB = acc;
  }
}

// ---------------- 16x16 LDS helpers (kD path, r9-proven, unchanged) ----------------
__device__ __forceinline__ short8 fragr(const u16t (*G)[40], int t, int c15, int g) {
  return *reinterpret_cast<const short8*>(&G[16 * t + c15][8 * g]);
}
__device__ __forceinline__ void stg_single(u16t (*G)[40], int col, int row, f32x4 v) {
  uint2 w; w.x = pack2_rn(v[0], v[1]); w.y = pack2_rn(v[2], v[3]);
  *reinterpret_cast<uint2*>(&G[col][row]) = w;
}
__device__ __forceinline__ void stg_split(u16t (*Gh)[40], u16t (*Gl)[40], int col, int row, f32x4 v) {
  u32t h0, l0, h1, l1;
  split2(v[0], v[1], h0, l0);
  split2(v[2], v[3], h1, l1);
  uint2 hv; hv.x = h0; hv.y = h1;
  uint2 lv; lv.x = l0; lv.y = l1;
  *reinterpret_cast<uint2*>(&Gh[col][row]) = hv;
  *reinterpret_cast<uint2*>(&Gl[col][row]) = lv;
}
__device__ __forceinline__ void load_sym_frags(const float* base, int c15, int g,
                                               short8* Fh, short8* Fl) {
#pragma unroll
  for (int t = 0; t < 2; ++t) {
    const float* sp = base + (16 * t + c15) * 32 + 8 * g;
    short8 hh, ll;
#pragma unroll
    for (int j = 0; j < 8; ++j) {
      u16t h, l;
      splitf(sp[j], h, l);
      hh[j] = (short)h;
      ll[j] = (short)l;
    }
    Fh[t] = hh;
    Fl[t] = ll;
  }
}

// ---------- tiny-kernel helpers (single block, 256 threads; r9-proven) ----------
__device__ __forceinline__ float dotrow36(const float* Arow, const float* v) {
  float s = 0.f;
#pragma unroll
  for (int j = 0; j < 8; ++j) {
    float4 a = *reinterpret_cast<const float4*>(Arow + 4 * j);
    s = fmaf(a.x, v[4 * j + 0], s);
    s = fmaf(a.y, v[4 * j + 1], s);
    s = fmaf(a.z, v[4 * j + 2], s);
    s = fmaf(a.w, v[4 * j + 3], s);
  }
  return s;
}
__device__ void mm64(float (*D)[LDSW], const float (*A)[LDSW], const float (*Bm)[LDSW], int tid) {
  const int h = tid >> 5, c = tid & 31;
  float bcol[32];
#pragma unroll
  for (int k = 0; k < 32; ++k) bcol[k] = Bm[k][c];
  float o[4];
#pragma unroll
  for (int i = 0; i < 4; ++i) o[i] = dotrow36(&A[4 * h + i][0], bcol);
  __syncthreads();
#pragma unroll
  for (int i = 0; i < 4; ++i) D[4 * h + i][c] = o[i];
  __syncthreads();
}
__device__ void ns_sqrt(LdsMat& Y, LdsMat& Z, LdsMat& Ya, LdsMat& Za, LdsMat T, int tid) {
  const int h = tid >> 5, c = tid & 31;
  for (int it = 0; it < NS_ITERS; ++it) {
    mm64(T, Z, Y, tid);
#pragma unroll
    for (int i = 0; i < 4; ++i) {
      int r = 4 * h + i;
      T[r][c] = ((r == c) ? 1.5f : 0.f) - 0.5f * T[r][c];
    }
    __syncthreads();
    mm64(Ya, Y, T, tid);
    mm64(Za, T, Z, tid);
    LdsMat t1 = Y; Y = Ya; Ya = t1;
    LdsMat t2 = Z; Z = Za; Za = t2;
  }
}

// ---------- kernels ----------

extern "C" __global__ void __launch_bounds__(256)
spdbn_kA(const float* __restrict__ x, float* __restrict__ wsf) {
  const int e  = (blockIdx.x & 3) * 256 + threadIdx.x;
  const int bs = blockIdx.x >> 2;
  float acc = 0.f;
  for (int t = 0; t < 64; ++t)
    acc += x[(size_t)(bs + 1024 * t) * 1024 + e];
  atomicAdd(&wsf[OFF_MEAN0 + e], acc);
}

extern "C" __global__ void __launch_bounds__(256)
spdbn_kS1(float* __restrict__ wsf) {
  __shared__ alignas(16) float W0[32][LDSW], W1[32][LDSW], W2[32][LDSW], W3[32][LDSW], W4[32][LDSW];
  const int tid = threadIdx.x, h = tid >> 5, c = tid & 31;
  float sacc = 0.f;
#pragma unroll
  for (int k = 0; k < 32; ++k) sacc += wsf[OFF_MEAN0 + 33 * k];
  const float cN = sacc / (32.f * (float)BATCH);
  const float scaleA = 32.f / sacc;
#pragma unroll
  for (int i = 0; i < 4; ++i) {
    int r = 4 * h + i;
    W1[r][c] = wsf[OFF_MEAN0 + r * 32 + c] * scaleA;
    W2[r][c] = (r == c) ? 1.f : 0.f;
  }
  __syncthreads();
  LdsMat Y = W1, Z = W2, Ya = W0, Za = W4;
  ns_sqrt(Y, Z, Ya, Za, W3, tid);
  const float sq = sqrtf(cN), rs = rsqrtf(cN);
#pragma unroll
  for (int i = 0; i < 4; ++i) {
    int r = 4 * h + i;
    wsf[OFF_INVS0 + r * 32 + c] = Z[r][c] * rs;
    wsf[OFF_S0    + r * 32 + c] = Y[r][c] * sq;
  }
  if (tid < 64) {
    const float PIF = 3.14159265358979f;
    const float th = ((float)tid + 0.5f) * (PIF / 64.f);
    const float t  = 0.5f * (CALPHA + CBETA) + 0.5f * (CBETA - CALPHA) * cosf(th);
    const float fl = logf(t);
    for (int j = 0; j < NCHEB; ++j) {
      float v = fl * cosf((float)j * th) * (2.f / 64.f);
#pragma unroll
      for (int off = 32; off >= 1; off >>= 1) v += __shfl_xor(v, off);
      if (tid == 0) wsf[OFF_CHEB + j] = (j == 0) ? 0.5f * v : v;
    }
  }
}

// Karcher step: accumulate sum_b log(inv_s0 x_b inv_s0)   [register-only core]
extern "C" __global__ void __launch_bounds__(64, 3)
spdbn_kB(const float* __restrict__ x, float* __restrict__ wsf) {
  const int lane = threadIdx.x, q = lane >> 5, n = lane & 31;
  short8 S_h[2], S_l[2];
  load_sym_frags32(wsf + OFF_INVS0, n, q, S_h, S_l);
  float cof[NCHEB];
#pragma unroll
  for (int k = 0; k < NCHEB; ++k) cof[k] = wsf[OFF_CHEB + k];
  f32x16 L;
#pragma unroll
  for (int rr = 0; rr < 16; ++rr) L[rr] = 0.f;
  for (int b = blockIdx.x; b < BATCH; b += gridDim.x)
    whiten_cheb32<true>(x + (size_t)b * 1024, S_h, S_l, cof, q, n, L);
#pragma unroll
  for (int rr = 0; rr < 16; ++rr)
    atomicAdd(&wsf[OFF_LOGAVG + ((rr & 3) + 8 * (rr >> 2) + 4 * q) * 32 + n], L[rr]);
}

extern "C" __global__ void __launch_bounds__(256)
spdbn_kS2(float* __restrict__ wsf, const float* __restrict__ shift) {
  __shared__ alignas(16) float W0[32][LDSW], W1[32][LDSW], W2[32][LDSW], W3[32][LDSW], W4[32][LDSW];
  const int tid = threadIdx.x, h = tid >> 5, c = tid & 31;
#pragma unroll
  for (int i = 0; i < 4; ++i) {
    int r = 4 * h + i;
    W0[r][c] = wsf[OFF_LOGAVG + r * 32 + c] * (1.f / (float)BATCH);
    W1[r][c] = (r == c) ? 1.f : 0.f;
  }
  __syncthreads();
  for (int j = EXP_TERMS; j >= 1; --j) {
    mm64(W3, W0, W1, tid);
    const float inv = 1.f / (float)j;
#pragma unroll
    for (int i = 0; i < 4; ++i) {
      int r = 4 * h + i;
      W1[r][c] = ((r == c) ? 1.f : 0.f) + W3[r][c] * inv;
    }
    __syncthreads();
  }
#pragma unroll
  for (int i = 0; i < 4; ++i) { int r = 4 * h + i; W2[r][c] = wsf[OFF_S0 + r * 32 + c]; }
  __syncthreads();
  mm64(W3, W2, W1, tid);
  mm64(W0, W3, W2, tid);
  float tr = 0.f;
#pragma unroll
  for (int k = 0; k < 32; ++k) tr += W0[k][k];
  tr *= (1.f / 32.f);
  const float itr = 1.f / tr;
#pragma unroll
  for (int i = 0; i < 4; ++i) {
    int r = 4 * h + i;
    W1[r][c] = W0[r][c] * itr;
    W2[r][c] = (r == c) ? 1.f : 0.f;
  }
  __syncthreads();
  LdsMat Y = W1, Z = W2, Ya = W0, Za = W4;
  ns_sqrt(Y, Z, Ya, Za, W3, tid);
  const float rs = rsqrtf(tr);
#pragma unroll
  for (int i = 0; i < 4; ++i) { int r = 4 * h + i; wsf[OFF_INVS + r * 32 + c] = Z[r][c] * rs; }
  __syncthreads();
  float tr2 = 0.f;
#pragma unroll
  for (int k = 0; k < 32; ++k) tr2 += shift[33 * k];
  tr2 *= (1.f / 32.f);
  const float itr2 = 1.f / tr2;
#pragma unroll
  for (int i = 0; i < 4; ++i) {
    int r = 4 * h + i;
    W1[r][c] = shift[r * 32 + c] * itr2;
    W2[r][c] = (r == c) ? 1.f : 0.f;
  }
  __syncthreads();
  LdsMat Y2 = W1, Z2 = W2, Ya2 = W0, Za2 = W4;
  ns_sqrt(Y2, Z2, Ya2, Za2, W3, tid);
  const float sq2 = sqrtf(tr2);
#pragma unroll
  for (int i = 0; i < 4; ++i) { int r = 4 * h + i; wsf[OFF_SSQRT + r * 32 + c] = Y2[r][c] * sq2; }
}

// BN whiten: L_b -> d_out (scratch); var += ||L_b||_F^2   [register-only core]
extern "C" __global__ void __launch_bounds__(64, 3)
spdbn_kC(const float* __restrict__ x, float* __restrict__ wsf, float* __restrict__ outL) {
  const int lane = threadIdx.x, q = lane >> 5, n = lane & 31;
  short8 S_h[2], S_l[2];
  load_sym_frags32(wsf + OFF_INVS, n, q, S_h, S_l);
  float cof[NCHEB];
#pragma unroll
  for (int k = 0; k < NCHEB; ++k) cof[k] = wsf[OFF_CHEB + k];
  float ss = 0.f;
  f32x16 L;
  for (int b = blockIdx.x; b < BATCH; b += gridDim.x) {
    whiten_cheb32<false>(x + (size_t)b * 1024, S_h, S_l, cof, q, n, L);
    float* ob = outL + (size_t)b * 1024;
#pragma unroll
    for (int rr = 0; rr < 16; ++rr) {
      float v = L[rr];
      ob[((rr & 3) + 8 * (rr >> 2) + 4 * q) * 32 + n] = v;
      ss = fmaf(v, v, ss);
    }
  }
#pragma unroll
  for (int off = 32; off >= 1; off >>= 1) ss += __shfl_xor(ss, off);
  if (lane == 0) atomicAdd(&wsf[OFF_VAR], ss);
}

extern "C" __global__ void spdbn_kS3(float* __restrict__ wsf, const float* __restrict__ scale) {
  if (threadIdx.x == 0) {
    float var = wsf[OFF_VAR] * (1.f / (float)BATCH);
    float stdv = sqrtf(var);
    wsf[OFF_P] = scale[0] / (stdv + 1e-5f);
  }
}

// out = s_sqrt * exp(p*L) * s_sqrt  (r9-proven path, unchanged)
extern "C" __global__ void __launch_bounds__(64, 3)
spdbn_kD(float* __restrict__ out, const float* __restrict__ wsf) {
  __shared__ alignas(16) u16t Xh[32][40], Xl[32][40], Bu0[32][40], Bu1[32][40];
  const int lane = threadIdx.x;
  const int g = lane >> 4, c15 = lane & 15;
  short8 Q_h[2], Q_l[2];
  load_sym_frags(wsf + OFF_SSQRT, c15, g, Q_h, Q_l);
  const float p = wsf[OFF_P];
  const f32x4 z4 = {0.f, 0.f, 0.f, 0.f};
  f32x4 dg4;
#pragma unroll
  for (int r = 0; r < 4; ++r) dg4[r] = (4 * g + r == c15) ? 1.f : 0.f;
  uint2 idp; idp.x = pack2_rn(dg4[0], dg4[1]); idp.y = pack2_rn(dg4[2], dg4[3]);
  uint2 zp;  zp.x = 0u; zp.y = 0u;
  for (int b = blockIdx.x; b < BATCH; b += MAIN_BLOCKS) {
    float* ob = out + (size_t)b * 1024;
#pragma unroll
    for (int e = 0; e < 4; ++e) {
      int idx = e * 256 + lane * 4;
      float4 v = *reinterpret_cast<const float4*>(ob + idx);
      int row = idx >> 5, col = idx & 31;
      u32t h0, l0, h1, l1;
      split2(v.x * p, v.y * p, h0, l0);
      split2(v.z * p, v.w * p, h1, l1);
      uint2 hv; hv.x = h0; hv.y = h1;
      uint2 lv; lv.x = l0; lv.y = l1;
      *reinterpret_cast<uint2*>(&Xh[row][col]) = hv;
      *reinterpret_cast<uint2*>(&Xl[row][col]) = lv;
    }
#pragma unroll
    for (int i = 0; i < 2; ++i)
#pragma unroll
      for (int j = 0; j < 2; ++j)
        *reinterpret_cast<uint2*>(&Bu0[16 * j + c15][16 * i + 4 * g]) = (i == j) ? idp : zp;
    __syncthreads();
    short8 Mh[2], Ml[2];
#pragma unroll
    for (int t = 0; t < 2; ++t) { Mh[t] = fragr(Xh, t, c15, g); Ml[t] = fragr(Xl, t, c15, g); }
    f32x4 acc[2][2];
#pragma unroll
    for (int jj = EXP_TERMS; jj >= 2; --jj) {
      const int t = EXP_TERMS - jj;
      const u16t (*R)[40] = (t & 1) ? Bu1 : Bu0;
      u16t (*W)[40]       = (t & 1) ? Bu0 : Bu1;
#pragma unroll
      for (int j = 0; j < 2; ++j) {
        short8 Bh = fragr(R, j, c15, g);
#pragma unroll
        for (int i = 0; i < 2; ++i) {
          f32x4 a = z4;
          a = MFMA16(Ml[i], Bh, a);
          a = MFMA16(Mh[i], Bh, a);
          acc[i][j] = a;
        }
      }
      const float inv = 1.f / (float)jj;
      __syncthreads();
#pragma unroll
      for (int i = 0; i < 2; ++i)
#pragma unroll
        for (int j = 0; j < 2; ++j) {
          f32x4 v;
#pragma unroll
          for (int r = 0; r < 4; ++r)
            v[r] = fmaf(acc[i][j][r], inv, ((16 * i + 4 * g + r) == (16 * j + c15)) ? 1.f : 0.f);
          stg_single(W, 16 * j + c15, 16 * i + 4 * g, v);
        }
      __syncthreads();
    }
#pragma unroll
    for (int j = 0; j < 2; ++j) {
      short8 Bh = fragr(Bu1, j, c15, g);
#pragma unroll
      for (int i = 0; i < 2; ++i) {
        f32x4 a = z4;
        a = MFMA16(Ml[i], Bh, a);
        a = MFMA16(Mh[i], Bh, a);
        acc[i][j] = a;
      }
    }
    __syncthreads();
#pragma unroll
    for (int i = 0; i < 2; ++i)
#pragma unroll
      for (int j = 0; j < 2; ++j) {
        f32x4 v;
#pragma unroll
        for (int r = 0; r < 4; ++r)
          v[r] = acc[i][j][r] + (((16 * i + 4 * g + r) == (16 * j + c15)) ? 1.f : 0.f);
        stg_split(Xh, Xl, 16 * j + c15, 16 * i + 4 * g, v);
      }
    __syncthreads();
    short8 Ph[2], Pl[2];
#pragma unroll
    for (int t = 0; t < 2; ++t) { Ph[t] = fragr(Xh, t, c15, g); Pl[t] = fragr(Xl, t, c15, g); }
#pragma unroll
    for (int i = 0; i < 2; ++i)
#pragma unroll
      for (int j = 0; j < 2; ++j) {
        f32x4 a = z4;
        a = MFMA16(Pl[i], Q_h[j], a);
        a = MFMA16(Ph[i], Q_l[j], a);
        a = MFMA16(Ph[i], Q_h[j], a);
        acc[i][j] = a;
      }
    __syncthreads();
#pragma unroll
    for (int i = 0; i < 2; ++i)
#pragma unroll
      for (int j = 0; j < 2; ++j)
        stg_split(Bu0, Bu1, 16 * j + c15, 16 * i + 4 * g, acc[i][j]);
    __syncthreads();
#pragma unroll
    for (int j = 0; j < 2; ++j) {
      short8 Wh = fragr(Bu0, j, c15, g), Wl = fragr(Bu1, j, c15, g);
#pragma unroll
      for (int i = 0; i < 2; ++i) {
        f32x4 a = z4;
        a = MFMA16(Q_l[i], Wh, a);
        a = MFMA16(Q_h[i], Wl, a);
        a = MFMA16(Q_h[i], Wh, a);
        acc[i][j] = a;
      }
    }
#pragma unroll
    for (int i = 0; i < 2; ++i)
#pragma unroll
      for (int j = 0; j < 2; ++j)
#pragma unroll
        for (int r = 0; r < 4; ++r)
          ob[(16 * i + 4 * g + r) * 32 + 16 * j + c15] = acc[i][j][r];
    __syncthreads();
  }
}

extern "C" void kernel_launch(void* const* d_in, const int* in_sizes, int n_in,
                              void* d_out, int out_size, void* d_ws, size_t ws_size,
                              hipStream_t stream) {
  const float* x     = (const float*)d_in[0];
  const float* shift = (const float*)d_in[1];
  const float* scale = (const float*)d_in[2];
  float* out = (float*)d_out;
  float* wsf = (float*)d_ws;

  size_t zbytes = 32768;
  if (ws_size < zbytes) zbytes = ws_size;
  hipMemsetAsync(d_ws, 0, zbytes, stream);

  hipLaunchKernelGGL(spdbn_kA,  dim3(4096),    dim3(256), 0, stream, x, wsf);
  hipLaunchKernelGGL(spdbn_kS1, dim3(1),       dim3(256), 0, stream, wsf);
  hipLaunchKernelGGL(spdbn_kB,  dim3(GRID_BC), dim3(64),  0, stream, x, wsf);
  hipLaunchKernelGGL(spdbn_kS2, dim3(1),       dim3(256), 0, stream, wsf, shift);
  hipLaunchKernelGGL(spdbn_kC,  dim3(GRID_BC), dim3(64),  0, stream, x, wsf, out);
  hipLaunchKernelGGL(spdbn_kS3, dim3(1),       dim3(64),  0, stream, wsf, scale);
  hipLaunchKernelGGL(spdbn_kD,  dim3(MAIN_BLOCKS), dim3(64), 0, stream, out, wsf);
}

// Round 13
// 655.877 us; speedup vs baseline: 1.0848x; 1.0848x over previous
//
#include <hip/hip_runtime.h>
#include <cstdint>
#include <cstddef>

#define BATCH       65536
#define LDSW        36          // padded LDS row stride for tiny-kernel matrices
#define NCHEB       16          // Chebyshev terms on [CALPHA, CBETA] (validated r7/r8)
#define CALPHA      0.28f
#define CBETA       4.6f
#define NS_ITERS    4
#define EXP_TERMS   8
#define MAIN_BLOCKS 3072        // kD grid (r9/r11-proven path)
#define GRID_BC     2048        // kB/kC: 2-matrix ILP, 16 pairs/block, 8 blocks/CU

// ws float offsets
#define OFF_MEAN0   0
#define OFF_INVS0   1024
#define OFF_S0      2048
#define OFF_LOGAVG  3072
#define OFF_INVS    4096
#define OFF_SSQRT   5120
#define OFF_VAR     6144
#define OFF_P       6145
#define OFF_CHEB    6152

typedef float (*LdsMat)[LDSW];
typedef __attribute__((ext_vector_type(8)))  short short8;
typedef __attribute__((ext_vector_type(4)))  float f32x4;
typedef __attribute__((ext_vector_type(16))) float f32x16;
typedef unsigned short u16t;
typedef unsigned int   u32t;

#define MFMA16(a, b, c) __builtin_amdgcn_mfma_f32_16x16x32_bf16((a), (b), (c), 0, 0, 0)
#define MFMA32(a, b, c) __builtin_amdgcn_mfma_f32_32x32x16_bf16((a), (b), (c), 0, 0, 0)

// ---------------- bf16 pack / split helpers (perm-based, proven r4-r11) ----------------
__device__ __forceinline__ u32t pack2_rn(float a, float b) {
  u32t ua = __float_as_uint(a) + 0x8000u;
  u32t ub = __float_as_uint(b) + 0x8000u;
  return __builtin_amdgcn_perm(ub, ua, 0x07060302u);
}
__device__ __forceinline__ void split2(float a, float b, u32t& hw, u32t& lw) {
  u32t ua = __float_as_uint(a) + 0x8000u;
  u32t ub = __float_as_uint(b) + 0x8000u;
  hw = __builtin_amdgcn_perm(ub, ua, 0x07060302u);
  float ra = a - __uint_as_float(ua & 0xFFFF0000u);
  float rb = b - __uint_as_float(ub & 0xFFFF0000u);
  lw = __builtin_amdgcn_perm(__float_as_uint(rb), __float_as_uint(ra), 0x07060302u);
}
__device__ __forceinline__ void split8regs(float4 a, float4 b, float mul, short8& hi, short8& lo) {
  u32t h0, l0, h1, l1, h2, l2, h3, l3;
  split2(a.x * mul, a.y * mul, h0, l0);
  split2(a.z * mul, a.w * mul, h1, l1);
  split2(b.x * mul, b.y * mul, h2, l2);
  split2(b.z * mul, b.w * mul, h3, l3);
  union { uint4 u; short8 s; } uh, ul;
  uh.u.x = h0; uh.u.y = h1; uh.u.z = h2; uh.u.w = h3;
  ul.u.x = l0; ul.u.y = l1; ul.u.z = l2; ul.u.w = l3;
  hi = uh.s; lo = ul.s;
}
__device__ __forceinline__ void splitf(float a, u16t& h, u16t& l) {
  unsigned u  = __float_as_uint(a);
  unsigned uh = (u + 0x8000u) & 0xFFFF0000u;
  float    r  = a - __uint_as_float(uh);
  unsigned ul = __float_as_uint(r) + 0x8000u;
  h = (u16t)(uh >> 16);
  l = (u16t)(ul >> 16);
}

// ---------------- 32x32 register-exchange helpers (r11-verified wiring) ----------------
// C-layout (32x32): lane = 32q + n holds D[row=(rr&3)+8(rr>>2)+4q][col=n], rr=0..15.
// B-frag (32x32x16, K-tile t): lane needs B[k=16t+8q+j][n], j=0..7.
// v_permlane32_swap(a,b): ret[0] = {a.row0 | b.row0->hi}, ret[1] = {a.row1->lo | b.row1}.
__device__ __forceinline__ void cmaj_to_bfrag(const f32x16& v, short8& f0, short8& f1) {
  u32t w[8];
#pragma unroll
  for (int d = 0; d < 8; ++d) w[d] = pack2_rn(v[2 * d], v[2 * d + 1]);
  auto r02 = __builtin_amdgcn_permlane32_swap(w[0], w[2], false, false);
  auto r13 = __builtin_amdgcn_permlane32_swap(w[1], w[3], false, false);
  auto r46 = __builtin_amdgcn_permlane32_swap(w[4], w[6], false, false);
  auto r57 = __builtin_amdgcn_permlane32_swap(w[5], w[7], false, false);
  union { uint4 u; short8 s; } A, B;
  A.u.x = r02[0]; A.u.y = r13[0]; A.u.z = r02[1]; A.u.w = r13[1];
  B.u.x = r46[0]; B.u.y = r57[0]; B.u.z = r46[1]; B.u.w = r57[1];
  f0 = A.s; f1 = B.s;
}
__device__ __forceinline__ void cmaj_to_bfrag_split(const f32x16& v,
    short8& f0h, short8& f1h, short8& f0l, short8& f1l) {
  u32t wh[8], wl[8];
#pragma unroll
  for (int d = 0; d < 8; ++d) split2(v[2 * d], v[2 * d + 1], wh[d], wl[d]);
  {
    auto r02 = __builtin_amdgcn_permlane32_swap(wh[0], wh[2], false, false);
    auto r13 = __builtin_amdgcn_permlane32_swap(wh[1], wh[3], false, false);
    auto r46 = __builtin_amdgcn_permlane32_swap(wh[4], wh[6], false, false);
    auto r57 = __builtin_amdgcn_permlane32_swap(wh[5], wh[7], false, false);
    union { uint4 u; short8 s; } A, B;
    A.u.x = r02[0]; A.u.y = r13[0]; A.u.z = r02[1]; A.u.w = r13[1];
    B.u.x = r46[0]; B.u.y = r57[0]; B.u.z = r46[1]; B.u.w = r57[1];
    f0h = A.s; f1h = B.s;
  }
  {
    auto r02 = __builtin_amdgcn_permlane32_swap(wl[0], wl[2], false, false);
    auto r13 = __builtin_amdgcn_permlane32_swap(wl[1], wl[3], false, false);
    auto r46 = __builtin_amdgcn_permlane32_swap(wl[4], wl[6], false, false);
    auto r57 = __builtin_amdgcn_permlane32_swap(wl[5], wl[7], false, false);
    union { uint4 u; short8 s; } A, B;
    A.u.x = r02[0]; A.u.y = r13[0]; A.u.z = r02[1]; A.u.w = r13[1];
    B.u.x = r46[0]; B.u.y = r57[0]; B.u.z = r46[1]; B.u.w = r57[1];
    f0l = A.s; f1l = B.s;
  }
}
// Cold: load symmetric 32x32 f32 -> A/B frags (row n, k = 16t+8q+j)
__device__ __forceinline__ void load_sym_frags32(const float* base, int n, int q,
                                                 short8* Fh, short8* Fl) {
#pragma unroll
  for (int t = 0; t < 2; ++t) {
    const float* sp = base + n * 32 + 16 * t + 8 * q;
    short8 hh, ll;
#pragma unroll
    for (int j = 0; j < 8; ++j) {
      u16t h, l;
      splitf(sp[j], h, l);
      hh[j] = (short)h;
      ll[j] = (short)l;
    }
    Fh[t] = hh;
    Fl[t] = ll;
  }
}

// ---------------- register-only whiten + Chebyshev, 2-matrix ILP (32x32 MFMA) ----------------
// Two independent chains interleaved: matrix-1's MFMAs hide matrix-0's cmaj VALU latency.
template <bool ACCUM>
__device__ __forceinline__ void whiten_cheb32_x2(
    const float* __restrict__ xb0, const float* __restrict__ xb1,
    const short8* S_h, const short8* S_l, const float* __restrict__ cof,
    int q, int n, f32x16& L0, f32x16& L1) {
  f32x16 z16;
#pragma unroll
  for (int rr = 0; rr < 16; ++rr) z16[rr] = 0.f;
  // 1. X A-frags direct from global (X symmetric) — both matrices, loads issued together
  short8 X0h[2], X0l[2], X1h[2], X1l[2];
  float4 a00, b00, a01, b01, a10, b10, a11, b11;
  {
    const float* p0 = xb0 + n * 32 + 8 * q;
    const float* p1 = xb1 + n * 32 + 8 * q;
    a00 = *reinterpret_cast<const float4*>(p0);
    b00 = *reinterpret_cast<const float4*>(p0 + 4);
    a01 = *reinterpret_cast<const float4*>(p0 + 16);
    b01 = *reinterpret_cast<const float4*>(p0 + 20);
    a10 = *reinterpret_cast<const float4*>(p1);
    b10 = *reinterpret_cast<const float4*>(p1 + 4);
    a11 = *reinterpret_cast<const float4*>(p1 + 16);
    b11 = *reinterpret_cast<const float4*>(p1 + 20);
  }
  split8regs(a00, b00, 1.f, X0h[0], X0l[0]);
  split8regs(a01, b01, 1.f, X0h[1], X0l[1]);
  split8regs(a10, b10, 1.f, X1h[0], X1l[0]);
  split8regs(a11, b11, 1.f, X1h[1], X1l[1]);
  // 2. V2 = X * S  (both)
  f32x16 v20 = z16, v21 = z16;
#pragma unroll
  for (int t = 0; t < 2; ++t) {
    v20 = MFMA32(X0l[t], S_h[t], v20);
    v21 = MFMA32(X1l[t], S_h[t], v21);
    v20 = MFMA32(X0h[t], S_l[t], v20);
    v21 = MFMA32(X1h[t], S_l[t], v21);
    v20 = MFMA32(X0h[t], S_h[t], v20);
    v21 = MFMA32(X1h[t], S_h[t], v21);
  }
  // 3. V2 B-frags (split) in registers (both)
  short8 V0h[2], V0l[2], V1h[2], V1l[2];
  cmaj_to_bfrag_split(v20, V0h[0], V0h[1], V0l[0], V0l[1]);
  cmaj_to_bfrag_split(v21, V1h[0], V1h[1], V1l[0], V1l[1]);
  // 4. Y = S * V2  (both)
  f32x16 y0 = z16, y1 = z16;
#pragma unroll
  for (int t = 0; t < 2; ++t) {
    y0 = MFMA32(S_l[t], V0h[t], y0);
    y1 = MFMA32(S_l[t], V1h[t], y1);
    y0 = MFMA32(S_h[t], V0l[t], y0);
    y1 = MFMA32(S_h[t], V1l[t], y1);
    y0 = MFMA32(S_h[t], V0h[t], y0);
    y1 = MFMA32(S_h[t], V1h[t], y1);
  }
  // 5. T1 = GSC*Y - MSH*I ; init L, nTm2 (both)
  const float GSC = 2.f / (CBETA - CALPHA);
  const float MSH = (CALPHA + CBETA) / (CBETA - CALPHA);
  const float c0 = cof[0], c1 = cof[1];
  f32x16 accB0, nTm20, accB1, nTm21;
#pragma unroll
  for (int rr = 0; rr < 16; ++rr) {
    int row = (rr & 3) + 8 * (rr >> 2) + 4 * q;
    float dgf = (row == n) ? 1.f : 0.f;
    float t10 = fmaf(y0[rr], GSC, -MSH * dgf);
    float t11 = fmaf(y1[rr], GSC, -MSH * dgf);
    accB0[rr] = t10;
    accB1[rr] = t11;
    nTm20[rr] = -dgf;
    nTm21[rr] = -dgf;
    float base0 = ACCUM ? L0[rr] : 0.f;
    float base1 = ACCUM ? L1[rr] : 0.f;
    L0[rr] = fmaf(c1, t10, fmaf(c0, dgf, base0));
    L1[rr] = fmaf(c1, t11, fmaf(c0, dgf, base1));
  }
  // A-frags of 2*Ytilde (symmetric), split (both)
  f32x16 y20, y21;
#pragma unroll
  for (int rr = 0; rr < 16; ++rr) { y20[rr] = accB0[rr] + accB0[rr]; y21[rr] = accB1[rr] + accB1[rr]; }
  short8 Y0h[2], Y0l[2], Y1h[2], Y1l[2];
  cmaj_to_bfrag_split(y20, Y0h[0], Y0h[1], Y0l[0], Y0l[1]);
  cmaj_to_bfrag_split(y21, Y1h[0], Y1h[1], Y1l[0], Y1l[1]);
  // 6. T_k = MFMA(2Yt, bf16(T_{k-1}), -T_{k-2}); L += c_k T_k  (chains interleaved)
#pragma unroll
  for (int k = 2; k < NCHEB; ++k) {
    short8 B00, B01, B10, B11;
    cmaj_to_bfrag(accB0, B00, B01);
    cmaj_to_bfrag(accB1, B10, B11);
    f32x16 acc0 = nTm20, acc1 = nTm21;
    acc0 = MFMA32(Y0l[0], B00, acc0);
    acc1 = MFMA32(Y1l[0], B10, acc1);
    acc0 = MFMA32(Y0h[0], B00, acc0);
    acc1 = MFMA32(Y1h[0], B10, acc1);
    acc0 = MFMA32(Y0l[1], B01, acc0);
    acc1 = MFMA32(Y1l[1], B11, acc1);
    acc0 = MFMA32(Y0h[1], B01, acc0);
    acc1 = MFMA32(Y1h[1], B11, acc1);
    const float ck = cof[k];
#pragma unroll
    for (int rr = 0; rr < 16; ++rr) {
      L0[rr]    = fmaf(ck, acc0[rr], L0[rr]);
      L1[rr]    = fmaf(ck, acc1[rr], L1[rr]);
      nTm20[rr] = -accB0[rr];
      nTm21[rr] = -accB1[rr];
    }
    accB0 = acc0;
    accB1 = acc1;
  }
}

// ---------------- 16x16 LDS helpers (kD path, r9-proven, unchanged) ----------------
__device__ __forceinline__ short8 fragr(const u16t (*G)[40], int t, int c15, int g) {
  return *reinterpret_cast<const short8*>(&G[16 * t + c15][8 * g]);
}
__device__ __forceinline__ void stg_single(u16t (*G)[40], int col, int row, f32x4 v) {
  uint2 w; w.x = pack2_rn(v[0], v[1]); w.y = pack2_rn(v[2], v[3]);
  *reinterpret_cast<uint2*>(&G[col][row]) = w;
}
__device__ __forceinline__ void stg_split(u16t (*Gh)[40], u16t (*Gl)[40], int col, int row, f32x4 v) {
  u32t h0, l0, h1, l1;
  split2(v[0], v[1], h0, l0);
  split2(v[2], v[3], h1, l1);
  uint2 hv; hv.x = h0; hv.y = h1;
  uint2 lv; lv.x = l0; lv.y = l1;
  *reinterpret_cast<uint2*>(&Gh[col][row]) = hv;
  *reinterpret_cast<uint2*>(&Gl[col][row]) = lv;
}
__device__ __forceinline__ void load_sym_frags(const float* base, int c15, int g,
                                               short8* Fh, short8* Fl) {
#pragma unroll
  for (int t = 0; t < 2; ++t) {
    const float* sp = base + (16 * t + c15) * 32 + 8 * g;
    short8 hh, ll;
#pragma unroll
    for (int j = 0; j < 8; ++j) {
      u16t h, l;
      splitf(sp[j], h, l);
      hh[j] = (short)h;
      ll[j] = (short)l;
    }
    Fh[t] = hh;
    Fl[t] = ll;
  }
}

// ---------- tiny-kernel helpers (single block, 256 threads; r9-proven) ----------
__device__ __forceinline__ float dotrow36(const float* Arow, const float* v) {
  float s = 0.f;
#pragma unroll
  for (int j = 0; j < 8; ++j) {
    float4 a = *reinterpret_cast<const float4*>(Arow + 4 * j);
    s = fmaf(a.x, v[4 * j + 0], s);
    s = fmaf(a.y, v[4 * j + 1], s);
    s = fmaf(a.z, v[4 * j + 2], s);
    s = fmaf(a.w, v[4 * j + 3], s);
  }
  return s;
}
__device__ void mm64(float (*D)[LDSW], const float (*A)[LDSW], const float (*Bm)[LDSW], int tid) {
  const int h = tid >> 5, c = tid & 31;
  float bcol[32];
#pragma unroll
  for (int k = 0; k < 32; ++k) bcol[k] = Bm[k][c];
  float o[4];
#pragma unroll
  for (int i = 0; i < 4; ++i) o[i] = dotrow36(&A[4 * h + i][0], bcol);
  __syncthreads();
#pragma unroll
  for (int i = 0; i < 4; ++i) D[4 * h + i][c] = o[i];
  __syncthreads();
}
__device__ void ns_sqrt(LdsMat& Y, LdsMat& Z, LdsMat& Ya, LdsMat& Za, LdsMat T, int tid) {
  const int h = tid >> 5, c = tid & 31;
  for (int it = 0; it < NS_ITERS; ++it) {
    mm64(T, Z, Y, tid);
#pragma unroll
    for (int i = 0; i < 4; ++i) {
      int r = 4 * h + i;
      T[r][c] = ((r == c) ? 1.5f : 0.f) - 0.5f * T[r][c];
    }
    __syncthreads();
    mm64(Ya, Y, T, tid);
    mm64(Za, T, Z, tid);
    LdsMat t1 = Y; Y = Ya; Ya = t1;
    LdsMat t2 = Z; Z = Za; Za = t2;
  }
}

// ---------- kernels ----------

extern "C" __global__ void __launch_bounds__(256)
spdbn_kA(const float* __restrict__ x, float* __restrict__ wsf) {
  const int e  = (blockIdx.x & 3) * 256 + threadIdx.x;
  const int bs = blockIdx.x >> 2;
  float acc = 0.f;
  for (int t = 0; t < 64; ++t)
    acc += x[(size_t)(bs + 1024 * t) * 1024 + e];
  atomicAdd(&wsf[OFF_MEAN0 + e], acc);
}

extern "C" __global__ void __launch_bounds__(256)
spdbn_kS1(float* __restrict__ wsf) {
  __shared__ alignas(16) float W0[32][LDSW], W1[32][LDSW], W2[32][LDSW], W3[32][LDSW], W4[32][LDSW];
  const int tid = threadIdx.x, h = tid >> 5, c = tid & 31;
  float sacc = 0.f;
#pragma unroll
  for (int k = 0; k < 32; ++k) sacc += wsf[OFF_MEAN0 + 33 * k];
  const float cN = sacc / (32.f * (float)BATCH);
  const float scaleA = 32.f / sacc;
#pragma unroll
  for (int i = 0; i < 4; ++i) {
    int r = 4 * h + i;
    W1[r][c] = wsf[OFF_MEAN0 + r * 32 + c] * scaleA;
    W2[r][c] = (r == c) ? 1.f : 0.f;
  }
  __syncthreads();
  LdsMat Y = W1, Z = W2, Ya = W0, Za = W4;
  ns_sqrt(Y, Z, Ya, Za, W3, tid);
  const float sq = sqrtf(cN), rs = rsqrtf(cN);
#pragma unroll
  for (int i = 0; i < 4; ++i) {
    int r = 4 * h + i;
    wsf[OFF_INVS0 + r * 32 + c] = Z[r][c] * rs;
    wsf[OFF_S0    + r * 32 + c] = Y[r][c] * sq;
  }
  if (tid < 64) {
    const float PIF = 3.14159265358979f;
    const float th = ((float)tid + 0.5f) * (PIF / 64.f);
    const float t  = 0.5f * (CALPHA + CBETA) + 0.5f * (CBETA - CALPHA) * cosf(th);
    const float fl = logf(t);
    for (int j = 0; j < NCHEB; ++j) {
      float v = fl * cosf((float)j * th) * (2.f / 64.f);
#pragma unroll
      for (int off = 32; off >= 1; off >>= 1) v += __shfl_xor(v, off);
      if (tid == 0) wsf[OFF_CHEB + j] = (j == 0) ? 0.5f * v : v;
    }
  }
}

// Karcher step: accumulate sum_b log(inv_s0 x_b inv_s0)   [register-only, 2-matrix ILP]
extern "C" __global__ void __launch_bounds__(64, 2)
spdbn_kB(const float* __restrict__ x, float* __restrict__ wsf) {
  const int lane = threadIdx.x, q = lane >> 5, n = lane & 31;
  short8 S_h[2], S_l[2];
  load_sym_frags32(wsf + OFF_INVS0, n, q, S_h, S_l);
  float cof[NCHEB];
#pragma unroll
  for (int k = 0; k < NCHEB; ++k) cof[k] = wsf[OFF_CHEB + k];
  f32x16 L0, L1;
#pragma unroll
  for (int rr = 0; rr < 16; ++rr) { L0[rr] = 0.f; L1[rr] = 0.f; }
  for (int b = blockIdx.x; b < BATCH / 2; b += gridDim.x)
    whiten_cheb32_x2<true>(x + (size_t)b * 1024, x + (size_t)(b + BATCH / 2) * 1024,
                           S_h, S_l, cof, q, n, L0, L1);
#pragma unroll
  for (int rr = 0; rr < 16; ++rr)
    atomicAdd(&wsf[OFF_LOGAVG + ((rr & 3) + 8 * (rr >> 2) + 4 * q) * 32 + n], L0[rr] + L1[rr]);
}

extern "C" __global__ void __launch_bounds__(256)
spdbn_kS2(float* __restrict__ wsf, const float* __restrict__ shift) {
  __shared__ alignas(16) float W0[32][LDSW], W1[32][LDSW], W2[32][LDSW], W3[32][LDSW], W4[32][LDSW];
  const int tid = threadIdx.x, h = tid >> 5, c = tid & 31;
#pragma unroll
  for (int i = 0; i < 4; ++i) {
    int r = 4 * h + i;
    W0[r][c] = wsf[OFF_LOGAVG + r * 32 + c] * (1.f / (float)BATCH);
    W1[r][c] = (r == c) ? 1.f : 0.f;
  }
  __syncthreads();
  for (int j = EXP_TERMS; j >= 1; --j) {
    mm64(W3, W0, W1, tid);
    const float inv = 1.f / (float)j;
#pragma unroll
    for (int i = 0; i < 4; ++i) {
      int r = 4 * h + i;
      W1[r][c] = ((r == c) ? 1.f : 0.f) + W3[r][c] * inv;
    }
    __syncthreads();
  }
#pragma unroll
  for (int i = 0; i < 4; ++i) { int r = 4 * h + i; W2[r][c] = wsf[OFF_S0 + r * 32 + c]; }
  __syncthreads();
  mm64(W3, W2, W1, tid);
  mm64(W0, W3, W2, tid);
  float tr = 0.f;
#pragma unroll
  for (int k = 0; k < 32; ++k) tr += W0[k][k];
  tr *= (1.f / 32.f);
  const float itr = 1.f / tr;
#pragma unroll
  for (int i = 0; i < 4; ++i) {
    int r = 4 * h + i;
    W1[r][c] = W0[r][c] * itr;
    W2[r][c] = (r == c) ? 1.f : 0.f;
  }
  __syncthreads();
  LdsMat Y = W1, Z = W2, Ya = W0, Za = W4;
  ns_sqrt(Y, Z, Ya, Za, W3, tid);
  const float rs = rsqrtf(tr);
#pragma unroll
  for (int i = 0; i < 4; ++i) { int r = 4 * h + i; wsf[OFF_INVS + r * 32 + c] = Z[r][c] * rs; }
  __syncthreads();
  float tr2 = 0.f;
#pragma unroll
  for (int k = 0; k < 32; ++k) tr2 += shift[33 * k];
  tr2 *= (1.f / 32.f);
  const float itr2 = 1.f / tr2;
#pragma unroll
  for (int i = 0; i < 4; ++i) {
    int r = 4 * h + i;
    W1[r][c] = shift[r * 32 + c] * itr2;
    W2[r][c] = (r == c) ? 1.f : 0.f;
  }
  __syncthreads();
  LdsMat Y2 = W1, Z2 = W2, Ya2 = W0, Za2 = W4;
  ns_sqrt(Y2, Z2, Ya2, Za2, W3, tid);
  const float sq2 = sqrtf(tr2);
#pragma unroll
  for (int i = 0; i < 4; ++i) { int r = 4 * h + i; wsf[OFF_SSQRT + r * 32 + c] = Y2[r][c] * sq2; }
}

// BN whiten: L_b -> d_out (scratch); var += ||L_b||_F^2   [register-only, 2-matrix ILP]
extern "C" __global__ void __launch_bounds__(64, 2)
spdbn_kC(const float* __restrict__ x, float* __restrict__ wsf, float* __restrict__ outL) {
  const int lane = threadIdx.x, q = lane >> 5, n = lane & 31;
  short8 S_h[2], S_l[2];
  load_sym_frags32(wsf + OFF_INVS, n, q, S_h, S_l);
  float cof[NCHEB];
#pragma unroll
  for (int k = 0; k < NCHEB; ++k) cof[k] = wsf[OFF_CHEB + k];
  float ss = 0.f;
  f32x16 L0, L1;
  for (int b = blockIdx.x; b < BATCH / 2; b += gridDim.x) {
    whiten_cheb32_x2<false>(x + (size_t)b * 1024, x + (size_t)(b + BATCH / 2) * 1024,
                            S_h, S_l, cof, q, n, L0, L1);
    float* ob0 = outL + (size_t)b * 1024;
    float* ob1 = outL + (size_t)(b + BATCH / 2) * 1024;
#pragma unroll
    for (int rr = 0; rr < 16; ++rr) {
      int off = ((rr & 3) + 8 * (rr >> 2) + 4 * q) * 32 + n;
      float v0 = L0[rr], v1 = L1[rr];
      ob0[off] = v0;
      ob1[off] = v1;
      ss = fmaf(v0, v0, ss);
      ss = fmaf(v1, v1, ss);
    }
  }
#pragma unroll
  for (int off = 32; off >= 1; off >>= 1) ss += __shfl_xor(ss, off);
  if (lane == 0) atomicAdd(&wsf[OFF_VAR], ss);
}

extern "C" __global__ void spdbn_kS3(float* __restrict__ wsf, const float* __restrict__ scale) {
  if (threadIdx.x == 0) {
    float var = wsf[OFF_VAR] * (1.f / (float)BATCH);
    float stdv = sqrtf(var);
    wsf[OFF_P] = scale[0] / (stdv + 1e-5f);
  }
}

// out = s_sqrt * exp(p*L) * s_sqrt  (r9/r11-proven path, unchanged)
extern "C" __global__ void __launch_bounds__(64, 3)
spdbn_kD(float* __restrict__ out, const float* __restrict__ wsf) {
  __shared__ alignas(16) u16t Xh[32][40], Xl[32][40], Bu0[32][40], Bu1[32][40];
  const int lane = threadIdx.x;
  const int g = lane >> 4, c15 = lane & 15;
  short8 Q_h[2], Q_l[2];
  load_sym_frags(wsf + OFF_SSQRT, c15, g, Q_h, Q_l);
  const float p = wsf[OFF_P];
  const f32x4 z4 = {0.f, 0.f, 0.f, 0.f};
  f32x4 dg4;
#pragma unroll
  for (int r = 0; r < 4; ++r) dg4[r] = (4 * g + r == c15) ? 1.f : 0.f;
  uint2 idp; idp.x = pack2_rn(dg4[0], dg4[1]); idp.y = pack2_rn(dg4[2], dg4[3]);
  uint2 zp;  zp.x = 0u; zp.y = 0u;
  for (int b = blockIdx.x; b < BATCH; b += MAIN_BLOCKS) {
    float* ob = out + (size_t)b * 1024;
#pragma unroll
    for (int e = 0; e < 4; ++e) {
      int idx = e * 256 + lane * 4;
      float4 v = *reinterpret_cast<const float4*>(ob + idx);
      int row = idx >> 5, col = idx & 31;
      u32t h0, l0, h1, l1;
      split2(v.x * p, v.y * p, h0, l0);
      split2(v.z * p, v.w * p, h1, l1);
      uint2 hv; hv.x = h0; hv.y = h1;
      uint2 lv; lv.x = l0; lv.y = l1;
      *reinterpret_cast<uint2*>(&Xh[row][col]) = hv;
      *reinterpret_cast<uint2*>(&Xl[row][col]) = lv;
    }
#pragma unroll
    for (int i = 0; i < 2; ++i)
#pragma unroll
      for (int j = 0; j < 2; ++j)
        *reinterpret_cast<uint2*>(&Bu0[16 * j + c15][16 * i + 4 * g]) = (i == j) ? idp : zp;
    __syncthreads();
    short8 Mh[2], Ml[2];
#pragma unroll
    for (int t = 0; t < 2; ++t) { Mh[t] = fragr(Xh, t, c15, g); Ml[t] = fragr(Xl, t, c15, g); }
    f32x4 acc[2][2];
#pragma unroll
    for (int jj = EXP_TERMS; jj >= 2; --jj) {
      const int t = EXP_TERMS - jj;
      const u16t (*R)[40] = (t & 1) ? Bu1 : Bu0;
      u16t (*W)[40]       = (t & 1) ? Bu0 : Bu1;
#pragma unroll
      for (int j = 0; j < 2; ++j) {
        short8 Bh = fragr(R, j, c15, g);
#pragma unroll
        for (int i = 0; i < 2; ++i) {
          f32x4 a = z4;
          a = MFMA16(Ml[i], Bh, a);
          a = MFMA16(Mh[i], Bh, a);
          acc[i][j] = a;
        }
      }
      const float inv = 1.f / (float)jj;
      __syncthreads();
#pragma unroll
      for (int i = 0; i < 2; ++i)
#pragma unroll
        for (int j = 0; j < 2; ++j) {
          f32x4 v;
#pragma unroll
          for (int r = 0; r < 4; ++r)
            v[r] = fmaf(acc[i][j][r], inv, ((16 * i + 4 * g + r) == (16 * j + c15)) ? 1.f : 0.f);
          stg_single(W, 16 * j + c15, 16 * i + 4 * g, v);
        }
      __syncthreads();
    }
#pragma unroll
    for (int j = 0; j < 2; ++j) {
      short8 Bh = fragr(Bu1, j, c15, g);
#pragma unroll
      for (int i = 0; i < 2; ++i) {
        f32x4 a = z4;
        a = MFMA16(Ml[i], Bh, a);
        a = MFMA16(Mh[i], Bh, a);
        acc[i][j] = a;
      }
    }
    __syncthreads();
#pragma unroll
    for (int i = 0; i < 2; ++i)
#pragma unroll
      for (int j = 0; j < 2; ++j) {
        f32x4 v;
#pragma unroll
        for (int r = 0; r < 4; ++r)
          v[r] = acc[i][j][r] + (((16 * i + 4 * g + r) == (16 * j + c15)) ? 1.f : 0.f);
        stg_split(Xh, Xl, 16 * j + c15, 16 * i + 4 * g, v);
      }
    __syncthreads();
    short8 Ph[2], Pl[2];
#pragma unroll
    for (int t = 0; t < 2; ++t) { Ph[t] = fragr(Xh, t, c15, g); Pl[t] = fragr(Xl, t, c15, g); }
#pragma unroll
    for (int i = 0; i < 2; ++i)
#pragma unroll
      for (int j = 0; j < 2; ++j) {
        f32x4 a = z4;
        a = MFMA16(Pl[i], Q_h[j], a);
        a = MFMA16(Ph[i], Q_l[j], a);
        a = MFMA16(Ph[i], Q_h[j], a);
        acc[i][j] = a;
      }
    __syncthreads();
#pragma unroll
    for (int i = 0; i < 2; ++i)
#pragma unroll
      for (int j = 0; j < 2; ++j)
        stg_split(Bu0, Bu1, 16 * j + c15, 16 * i + 4 * g, acc[i][j]);
    __syncthreads();
#pragma unroll
    for (int j = 0; j < 2; ++j) {
      short8 Wh = fragr(Bu0, j, c15, g), Wl = fragr(Bu1, j, c15, g);
#pragma unroll
      for (int i = 0; i < 2; ++i) {
        f32x4 a = z4;
        a = MFMA16(Q_l[i], Wh, a);
        a = MFMA16(Q_h[i], Wl, a);
        a = MFMA16(Q_h[i], Wh, a);
        acc[i][j] = a;
      }
    }
#pragma unroll
    for (int i = 0; i < 2; ++i)
#pragma unroll
      for (int j = 0; j < 2; ++j)
#pragma unroll
        for (int r = 0; r < 4; ++r)
          ob[(16 * i + 4 * g + r) * 32 + 16 * j + c15] = acc[i][j][r];
    __syncthreads();
  }
}

extern "C" void kernel_launch(void* const* d_in, const int* in_sizes, int n_in,
                              void* d_out, int out_size, void* d_ws, size_t ws_size,
                              hipStream_t stream) {
  const float* x     = (const float*)d_in[0];
  const float* shift = (const float*)d_in[1];
  const float* scale = (const float*)d_in[2];
  float* out = (float*)d_out;
  float* wsf = (float*)d_ws;

  size_t zbytes = 32768;
  if (ws_size < zbytes) zbytes = ws_size;
  hipMemsetAsync(d_ws, 0, zbytes, stream);

  hipLaunchKernelGGL(spdbn_kA,  dim3(4096),    dim3(256), 0, stream, x, wsf);
  hipLaunchKernelGGL(spdbn_kS1, dim3(1),       dim3(256), 0, stream, wsf);
  hipLaunchKernelGGL(spdbn_kB,  dim3(GRID_BC), dim3(64),  0, stream, x, wsf);
  hipLaunchKernelGGL(spdbn_kS2, dim3(1),       dim3(256), 0, stream, wsf, shift);
  hipLaunchKernelGGL(spdbn_kC,  dim3(GRID_BC), dim3(64),  0, stream, x, wsf, out);
  hipLaunchKernelGGL(spdbn_kS3, dim3(1),       dim3(64),  0, stream, wsf, scale);
  hipLaunchKernelGGL(spdbn_kD,  dim3(MAIN_BLOCKS), dim3(64), 0, stream, out, wsf);
}

// Round 14
// 627.962 us; speedup vs baseline: 1.1330x; 1.0445x over previous
//
#include <hip/hip_runtime.h>
#include <cstdint>
#include <cstddef>

#define BATCH       65536
#define LDSW        36          // padded LDS row stride for tiny-kernel matrices
#define NCHEB       16          // Chebyshev terms on [CALPHA, CBETA] (validated r7/r8)
#define CALPHA      0.28f
#define CBETA       4.6f
#define NS_ITERS    4
#define EXP_TERMS   8
#define MAIN_BLOCKS 3072        // kD grid (r9/r11-proven path)
#define GRID_BC     2048        // kB/kC: 2-matrix ILP, 16 pairs/block

// ws float offsets
#define OFF_MEAN0   0
#define OFF_INVS0   1024
#define OFF_S0      2048
#define OFF_LOGAVG  3072
#define OFF_INVS    4096
#define OFF_SSQRT   5120
#define OFF_VAR     6144
#define OFF_P       6145
#define OFF_CHEB    6152

typedef float (*LdsMat)[LDSW];
typedef __attribute__((ext_vector_type(8)))  short short8;
typedef __attribute__((ext_vector_type(4)))  float f32x4;
typedef __attribute__((ext_vector_type(16))) float f32x16;
typedef unsigned short u16t;
typedef unsigned int   u32t;

#define MFMA16(a, b, c) __builtin_amdgcn_mfma_f32_16x16x32_bf16((a), (b), (c), 0, 0, 0)
#define MFMA32(a, b, c) __builtin_amdgcn_mfma_f32_32x32x16_bf16((a), (b), (c), 0, 0, 0)

// ---------------- bf16 pack / split helpers (perm-based, proven r4-r13) ----------------
__device__ __forceinline__ u32t pack2_rn(float a, float b) {
  u32t ua = __float_as_uint(a) + 0x8000u;
  u32t ub = __float_as_uint(b) + 0x8000u;
  return __builtin_amdgcn_perm(ub, ua, 0x07060302u);
}
__device__ __forceinline__ void split2(float a, float b, u32t& hw, u32t& lw) {
  u32t ua = __float_as_uint(a) + 0x8000u;
  u32t ub = __float_as_uint(b) + 0x8000u;
  hw = __builtin_amdgcn_perm(ub, ua, 0x07060302u);
  float ra = a - __uint_as_float(ua & 0xFFFF0000u);
  float rb = b - __uint_as_float(ub & 0xFFFF0000u);
  lw = __builtin_amdgcn_perm(__float_as_uint(rb), __float_as_uint(ra), 0x07060302u);
}
__device__ __forceinline__ void split8regs(float4 a, float4 b, float mul, short8& hi, short8& lo) {
  u32t h0, l0, h1, l1, h2, l2, h3, l3;
  split2(a.x * mul, a.y * mul, h0, l0);
  split2(a.z * mul, a.w * mul, h1, l1);
  split2(b.x * mul, b.y * mul, h2, l2);
  split2(b.z * mul, b.w * mul, h3, l3);
  union { uint4 u; short8 s; } uh, ul;
  uh.u.x = h0; uh.u.y = h1; uh.u.z = h2; uh.u.w = h3;
  ul.u.x = l0; ul.u.y = l1; ul.u.z = l2; ul.u.w = l3;
  hi = uh.s; lo = ul.s;
}
__device__ __forceinline__ void splitf(float a, u16t& h, u16t& l) {
  unsigned u  = __float_as_uint(a);
  unsigned uh = (u + 0x8000u) & 0xFFFF0000u;
  float    r  = a - __uint_as_float(uh);
  unsigned ul = __float_as_uint(r) + 0x8000u;
  h = (u16t)(uh >> 16);
  l = (u16t)(ul >> 16);
}
// exact bf16 negation of a packed fragment (XOR sign bits)
__device__ __forceinline__ short8 neg8(short8 v) {
  union { uint4 u; short8 s; } a;
  a.s = v;
  a.u.x ^= 0x80008000u; a.u.y ^= 0x80008000u;
  a.u.z ^= 0x80008000u; a.u.w ^= 0x80008000u;
  return a.s;
}

// ---------------- 32x32 register-exchange helpers (r11-verified wiring) ----------------
// C-layout (32x32): lane = 32q + n holds D[row=(rr&3)+8(rr>>2)+4q][col=n], rr=0..15.
// B-frag (32x32x16, K-tile t): lane needs B[k=16t+8q+j][n], j=0..7.
__device__ __forceinline__ void cmaj_to_bfrag(const f32x16& v, short8& f0, short8& f1) {
  u32t w[8];
#pragma unroll
  for (int d = 0; d < 8; ++d) w[d] = pack2_rn(v[2 * d], v[2 * d + 1]);
  auto r02 = __builtin_amdgcn_permlane32_swap(w[0], w[2], false, false);
  auto r13 = __builtin_amdgcn_permlane32_swap(w[1], w[3], false, false);
  auto r46 = __builtin_amdgcn_permlane32_swap(w[4], w[6], false, false);
  auto r57 = __builtin_amdgcn_permlane32_swap(w[5], w[7], false, false);
  union { uint4 u; short8 s; } A, B;
  A.u.x = r02[0]; A.u.y = r13[0]; A.u.z = r02[1]; A.u.w = r13[1];
  B.u.x = r46[0]; B.u.y = r57[0]; B.u.z = r46[1]; B.u.w = r57[1];
  f0 = A.s; f1 = B.s;
}
__device__ __forceinline__ void cmaj_to_bfrag_split(const f32x16& v,
    short8& f0h, short8& f1h, short8& f0l, short8& f1l) {
  u32t wh[8], wl[8];
#pragma unroll
  for (int d = 0; d < 8; ++d) split2(v[2 * d], v[2 * d + 1], wh[d], wl[d]);
  {
    auto r02 = __builtin_amdgcn_permlane32_swap(wh[0], wh[2], false, false);
    auto r13 = __builtin_amdgcn_permlane32_swap(wh[1], wh[3], false, false);
    auto r46 = __builtin_amdgcn_permlane32_swap(wh[4], wh[6], false, false);
    auto r57 = __builtin_amdgcn_permlane32_swap(wh[5], wh[7], false, false);
    union { uint4 u; short8 s; } A, B;
    A.u.x = r02[0]; A.u.y = r13[0]; A.u.z = r02[1]; A.u.w = r13[1];
    B.u.x = r46[0]; B.u.y = r57[0]; B.u.z = r46[1]; B.u.w = r57[1];
    f0h = A.s; f1h = B.s;
  }
  {
    auto r02 = __builtin_amdgcn_permlane32_swap(wl[0], wl[2], false, false);
    auto r13 = __builtin_amdgcn_permlane32_swap(wl[1], wl[3], false, false);
    auto r46 = __builtin_amdgcn_permlane32_swap(wl[4], wl[6], false, false);
    auto r57 = __builtin_amdgcn_permlane32_swap(wl[5], wl[7], false, false);
    union { uint4 u; short8 s; } A, B;
    A.u.x = r02[0]; A.u.y = r13[0]; A.u.z = r02[1]; A.u.w = r13[1];
    B.u.x = r46[0]; B.u.y = r57[0]; B.u.z = r46[1]; B.u.w = r57[1];
    f0l = A.s; f1l = B.s;
  }
}
// Cold: load symmetric 32x32 f32 -> A/B frags (row n, k = 16t+8q+j)
__device__ __forceinline__ void load_sym_frags32(const float* base, int n, int q,
                                                 short8* Fh, short8* Fl) {
#pragma unroll
  for (int t = 0; t < 2; ++t) {
    const float* sp = base + n * 32 + 16 * t + 8 * q;
    short8 hh, ll;
#pragma unroll
    for (int j = 0; j < 8; ++j) {
      u16t h, l;
      splitf(sp[j], h, l);
      hh[j] = (short)h;
      ll[j] = (short)l;
    }
    Fh[t] = hh;
    Fl[t] = ll;
  }
}

// ---------------- register-only whiten + Chebyshev, 2-matrix ILP, sign-alternating ----------------
// X_k = (-1)^floor(k/2) T_k satisfies X_k = MFMA(A_k, X_{k-1}, C=+X_{k-2}),
// A_k = -2Yt (k even) / +2Yt (k odd) -> no per-step negation. cof[] pre-sign-folded.
template <bool ACCUM>
__device__ __forceinline__ void whiten_cheb32_x2(
    const float* __restrict__ xb0, const float* __restrict__ xb1,
    const short8* S_h, const short8* S_l, const float* __restrict__ cof,
    int q, int n, f32x16& L0, f32x16& L1) {
  f32x16 z16;
#pragma unroll
  for (int rr = 0; rr < 16; ++rr) z16[rr] = 0.f;
  // 1. X A-frags direct from global (X symmetric)
  short8 X0h[2], X0l[2], X1h[2], X1l[2];
  float4 a00, b00, a01, b01, a10, b10, a11, b11;
  {
    const float* p0 = xb0 + n * 32 + 8 * q;
    const float* p1 = xb1 + n * 32 + 8 * q;
    a00 = *reinterpret_cast<const float4*>(p0);
    b00 = *reinterpret_cast<const float4*>(p0 + 4);
    a01 = *reinterpret_cast<const float4*>(p0 + 16);
    b01 = *reinterpret_cast<const float4*>(p0 + 20);
    a10 = *reinterpret_cast<const float4*>(p1);
    b10 = *reinterpret_cast<const float4*>(p1 + 4);
    a11 = *reinterpret_cast<const float4*>(p1 + 16);
    b11 = *reinterpret_cast<const float4*>(p1 + 20);
  }
  split8regs(a00, b00, 1.f, X0h[0], X0l[0]);
  split8regs(a01, b01, 1.f, X0h[1], X0l[1]);
  split8regs(a10, b10, 1.f, X1h[0], X1l[0]);
  split8regs(a11, b11, 1.f, X1h[1], X1l[1]);
  // 2. V2 = X * S
  f32x16 v20 = z16, v21 = z16;
#pragma unroll
  for (int t = 0; t < 2; ++t) {
    v20 = MFMA32(X0l[t], S_h[t], v20);
    v21 = MFMA32(X1l[t], S_h[t], v21);
    v20 = MFMA32(X0h[t], S_l[t], v20);
    v21 = MFMA32(X1h[t], S_l[t], v21);
    v20 = MFMA32(X0h[t], S_h[t], v20);
    v21 = MFMA32(X1h[t], S_h[t], v21);
  }
  // 3. V2 B-frags (split)
  short8 V0h[2], V0l[2], V1h[2], V1l[2];
  cmaj_to_bfrag_split(v20, V0h[0], V0h[1], V0l[0], V0l[1]);
  cmaj_to_bfrag_split(v21, V1h[0], V1h[1], V1l[0], V1l[1]);
  // 4. Y = S * V2
  f32x16 y0 = z16, y1 = z16;
#pragma unroll
  for (int t = 0; t < 2; ++t) {
    y0 = MFMA32(S_l[t], V0h[t], y0);
    y1 = MFMA32(S_l[t], V1h[t], y1);
    y0 = MFMA32(S_h[t], V0l[t], y0);
    y1 = MFMA32(S_h[t], V1l[t], y1);
    y0 = MFMA32(S_h[t], V0h[t], y0);
    y1 = MFMA32(S_h[t], V1h[t], y1);
  }
  // 5. T1 = GSC*Y - MSH*I ; init L, X_{k-2}=T0=I, X_{k-1}=T1
  const float GSC = 2.f / (CBETA - CALPHA);
  const float MSH = (CALPHA + CBETA) / (CBETA - CALPHA);
  const float c0 = cof[0], c1 = cof[1];
  f32x16 Xm1_0, Xm2_0, Xm1_1, Xm2_1;
#pragma unroll
  for (int rr = 0; rr < 16; ++rr) {
    int row = (rr & 3) + 8 * (rr >> 2) + 4 * q;
    float dgf = (row == n) ? 1.f : 0.f;
    float t10 = fmaf(y0[rr], GSC, -MSH * dgf);
    float t11 = fmaf(y1[rr], GSC, -MSH * dgf);
    Xm1_0[rr] = t10;
    Xm1_1[rr] = t11;
    Xm2_0[rr] = dgf;
    Xm2_1[rr] = dgf;
    float base0 = ACCUM ? L0[rr] : 0.f;
    float base1 = ACCUM ? L1[rr] : 0.f;
    L0[rr] = fmaf(c1, t10, fmaf(c0, dgf, base0));
    L1[rr] = fmaf(c1, t11, fmaf(c0, dgf, base1));
  }
  // A-frags of +2*Ytilde (split) and exact bf16 negation (-2*Ytilde)
  f32x16 y20, y21;
#pragma unroll
  for (int rr = 0; rr < 16; ++rr) { y20[rr] = Xm1_0[rr] + Xm1_0[rr]; y21[rr] = Xm1_1[rr] + Xm1_1[rr]; }
  short8 Y0h[2], Y0l[2], Y1h[2], Y1l[2];
  cmaj_to_bfrag_split(y20, Y0h[0], Y0h[1], Y0l[0], Y0l[1]);
  cmaj_to_bfrag_split(y21, Y1h[0], Y1h[1], Y1l[0], Y1l[1]);
  short8 N0h[2], N0l[2], N1h[2], N1l[2];
#pragma unroll
  for (int t = 0; t < 2; ++t) {
    N0h[t] = neg8(Y0h[t]); N0l[t] = neg8(Y0l[t]);
    N1h[t] = neg8(Y1h[t]); N1l[t] = neg8(Y1l[t]);
  }
  // 6. X_k = MFMA(A_k, X_{k-1}, X_{k-2}); L += cof'[k] X_k   (chains interleaved)
#pragma unroll
  for (int k = 2; k < NCHEB; ++k) {
    const bool odd = (k & 1) != 0;         // compile-time in unrolled loop
    short8 B00, B01, B10, B11;
    cmaj_to_bfrag(Xm1_0, B00, B01);
    cmaj_to_bfrag(Xm1_1, B10, B11);
    short8 A0l0 = odd ? Y0l[0] : N0l[0];
    short8 A0h0 = odd ? Y0h[0] : N0h[0];
    short8 A0l1 = odd ? Y0l[1] : N0l[1];
    short8 A0h1 = odd ? Y0h[1] : N0h[1];
    short8 A1l0 = odd ? Y1l[0] : N1l[0];
    short8 A1h0 = odd ? Y1h[0] : N1h[0];
    short8 A1l1 = odd ? Y1l[1] : N1l[1];
    short8 A1h1 = odd ? Y1h[1] : N1h[1];
    f32x16 acc0 = Xm2_0, acc1 = Xm2_1;
    acc0 = MFMA32(A0l0, B00, acc0);
    acc1 = MFMA32(A1l0, B10, acc1);
    acc0 = MFMA32(A0h0, B00, acc0);
    acc1 = MFMA32(A1h0, B10, acc1);
    acc0 = MFMA32(A0l1, B01, acc0);
    acc1 = MFMA32(A1l1, B11, acc1);
    acc0 = MFMA32(A0h1, B01, acc0);
    acc1 = MFMA32(A1h1, B11, acc1);
    const float ck = cof[k];
#pragma unroll
    for (int rr = 0; rr < 16; ++rr) {
      L0[rr] = fmaf(ck, acc0[rr], L0[rr]);
      L1[rr] = fmaf(ck, acc1[rr], L1[rr]);
    }
    Xm2_0 = Xm1_0; Xm1_0 = acc0;
    Xm2_1 = Xm1_1; Xm1_1 = acc1;
  }
}

// ---------------- 16x16 LDS helpers (kD path, r9-proven, unchanged) ----------------
__device__ __forceinline__ short8 fragr(const u16t (*G)[40], int t, int c15, int g) {
  return *reinterpret_cast<const short8*>(&G[16 * t + c15][8 * g]);
}
__device__ __forceinline__ void stg_single(u16t (*G)[40], int col, int row, f32x4 v) {
  uint2 w; w.x = pack2_rn(v[0], v[1]); w.y = pack2_rn(v[2], v[3]);
  *reinterpret_cast<uint2*>(&G[col][row]) = w;
}
__device__ __forceinline__ void stg_split(u16t (*Gh)[40], u16t (*Gl)[40], int col, int row, f32x4 v) {
  u32t h0, l0, h1, l1;
  split2(v[0], v[1], h0, l0);
  split2(v[2], v[3], h1, l1);
  uint2 hv; hv.x = h0; hv.y = h1;
  uint2 lv; lv.x = l0; lv.y = l1;
  *reinterpret_cast<uint2*>(&Gh[col][row]) = hv;
  *reinterpret_cast<uint2*>(&Gl[col][row]) = lv;
}
__device__ __forceinline__ void load_sym_frags(const float* base, int c15, int g,
                                               short8* Fh, short8* Fl) {
#pragma unroll
  for (int t = 0; t < 2; ++t) {
    const float* sp = base + (16 * t + c15) * 32 + 8 * g;
    short8 hh, ll;
#pragma unroll
    for (int j = 0; j < 8; ++j) {
      u16t h, l;
      splitf(sp[j], h, l);
      hh[j] = (short)h;
      ll[j] = (short)l;
    }
    Fh[t] = hh;
    Fl[t] = ll;
  }
}

// ---------- tiny-kernel helpers (single block, 256 threads; r9-proven) ----------
__device__ __forceinline__ float dotrow36(const float* Arow, const float* v) {
  float s = 0.f;
#pragma unroll
  for (int j = 0; j < 8; ++j) {
    float4 a = *reinterpret_cast<const float4*>(Arow + 4 * j);
    s = fmaf(a.x, v[4 * j + 0], s);
    s = fmaf(a.y, v[4 * j + 1], s);
    s = fmaf(a.z, v[4 * j + 2], s);
    s = fmaf(a.w, v[4 * j + 3], s);
  }
  return s;
}
__device__ void mm64(float (*D)[LDSW], const float (*A)[LDSW], const float (*Bm)[LDSW], int tid) {
  const int h = tid >> 5, c = tid & 31;
  float bcol[32];
#pragma unroll
  for (int k = 0; k < 32; ++k) bcol[k] = Bm[k][c];
  float o[4];
#pragma unroll
  for (int i = 0; i < 4; ++i) o[i] = dotrow36(&A[4 * h + i][0], bcol);
  __syncthreads();
#pragma unroll
  for (int i = 0; i < 4; ++i) D[4 * h + i][c] = o[i];
  __syncthreads();
}
__device__ void ns_sqrt(LdsMat& Y, LdsMat& Z, LdsMat& Ya, LdsMat& Za, LdsMat T, int tid) {
  const int h = tid >> 5, c = tid & 31;
  for (int it = 0; it < NS_ITERS; ++it) {
    mm64(T, Z, Y, tid);
#pragma unroll
    for (int i = 0; i < 4; ++i) {
      int r = 4 * h + i;
      T[r][c] = ((r == c) ? 1.5f : 0.f) - 0.5f * T[r][c];
    }
    __syncthreads();
    mm64(Ya, Y, T, tid);
    mm64(Za, T, Z, tid);
    LdsMat t1 = Y; Y = Ya; Ya = t1;
    LdsMat t2 = Z; Z = Za; Za = t2;
  }
}

// ---------- kernels ----------

extern "C" __global__ void __launch_bounds__(256)
spdbn_kA(const float* __restrict__ x, float* __restrict__ wsf) {
  const int e  = (blockIdx.x & 3) * 256 + threadIdx.x;
  const int bs = blockIdx.x >> 2;
  float acc = 0.f;
  for (int t = 0; t < 64; ++t)
    acc += x[(size_t)(bs + 1024 * t) * 1024 + e];
  atomicAdd(&wsf[OFF_MEAN0 + e], acc);
}

extern "C" __global__ void __launch_bounds__(256)
spdbn_kS1(float* __restrict__ wsf) {
  __shared__ alignas(16) float W0[32][LDSW], W1[32][LDSW], W2[32][LDSW], W3[32][LDSW], W4[32][LDSW];
  const int tid = threadIdx.x, h = tid >> 5, c = tid & 31;
  float sacc = 0.f;
#pragma unroll
  for (int k = 0; k < 32; ++k) sacc += wsf[OFF_MEAN0 + 33 * k];
  const float cN = sacc / (32.f * (float)BATCH);
  const float scaleA = 32.f / sacc;
#pragma unroll
  for (int i = 0; i < 4; ++i) {
    int r = 4 * h + i;
    W1[r][c] = wsf[OFF_MEAN0 + r * 32 + c] * scaleA;
    W2[r][c] = (r == c) ? 1.f : 0.f;
  }
  __syncthreads();
  LdsMat Y = W1, Z = W2, Ya = W0, Za = W4;
  ns_sqrt(Y, Z, Ya, Za, W3, tid);
  const float sq = sqrtf(cN), rs = rsqrtf(cN);
#pragma unroll
  for (int i = 0; i < 4; ++i) {
    int r = 4 * h + i;
    wsf[OFF_INVS0 + r * 32 + c] = Z[r][c] * rs;
    wsf[OFF_S0    + r * 32 + c] = Y[r][c] * sq;
  }
  if (tid < 64) {
    const float PIF = 3.14159265358979f;
    const float th = ((float)tid + 0.5f) * (PIF / 64.f);
    const float t  = 0.5f * (CALPHA + CBETA) + 0.5f * (CBETA - CALPHA) * cosf(th);
    const float fl = logf(t);
    for (int j = 0; j < NCHEB; ++j) {
      float v = fl * cosf((float)j * th) * (2.f / 64.f);
#pragma unroll
      for (int off = 32; off >= 1; off >>= 1) v += __shfl_xor(v, off);
      if (tid == 0) wsf[OFF_CHEB + j] = (j == 0) ? 0.5f * v : v;
    }
  }
}

// Karcher step: accumulate sum_b log(inv_s0 x_b inv_s0)   [register-only, 2-ILP, sign-alt]
extern "C" __global__ void __launch_bounds__(64, 2)
spdbn_kB(const float* __restrict__ x, float* __restrict__ wsf) {
  const int lane = threadIdx.x, q = lane >> 5, n = lane & 31;
  short8 S_h[2], S_l[2];
  load_sym_frags32(wsf + OFF_INVS0, n, q, S_h, S_l);
  float cof[NCHEB];
#pragma unroll
  for (int k = 0; k < NCHEB; ++k) {
    float sg = ((k >> 1) & 1) ? -1.f : 1.f;   // fold (-1)^floor(k/2) into coeffs
    cof[k] = wsf[OFF_CHEB + k] * sg;
  }
  f32x16 L0, L1;
#pragma unroll
  for (int rr = 0; rr < 16; ++rr) { L0[rr] = 0.f; L1[rr] = 0.f; }
  for (int b = blockIdx.x; b < BATCH / 2; b += gridDim.x)
    whiten_cheb32_x2<true>(x + (size_t)b * 1024, x + (size_t)(b + BATCH / 2) * 1024,
                           S_h, S_l, cof, q, n, L0, L1);
#pragma unroll
  for (int rr = 0; rr < 16; ++rr)
    atomicAdd(&wsf[OFF_LOGAVG + ((rr & 3) + 8 * (rr >> 2) + 4 * q) * 32 + n], L0[rr] + L1[rr]);
}

extern "C" __global__ void __launch_bounds__(256)
spdbn_kS2(float* __restrict__ wsf, const float* __restrict__ shift) {
  __shared__ alignas(16) float W0[32][LDSW], W1[32][LDSW], W2[32][LDSW], W3[32][LDSW], W4[32][LDSW];
  const int tid = threadIdx.x, h = tid >> 5, c = tid & 31;
#pragma unroll
  for (int i = 0; i < 4; ++i) {
    int r = 4 * h + i;
    W0[r][c] = wsf[OFF_LOGAVG + r * 32 + c] * (1.f / (float)BATCH);
    W1[r][c] = (r == c) ? 1.f : 0.f;
  }
  __syncthreads();
  for (int j = EXP_TERMS; j >= 1; --j) {
    mm64(W3, W0, W1, tid);
    const float inv = 1.f / (float)j;
#pragma unroll
    for (int i = 0; i < 4; ++i) {
      int r = 4 * h + i;
      W1[r][c] = ((r == c) ? 1.f : 0.f) + W3[r][c] * inv;
    }
    __syncthreads();
  }
#pragma unroll
  for (int i = 0; i < 4; ++i) { int r = 4 * h + i; W2[r][c] = wsf[OFF_S0 + r * 32 + c]; }
  __syncthreads();
  mm64(W3, W2, W1, tid);
  mm64(W0, W3, W2, tid);
  float tr = 0.f;
#pragma unroll
  for (int k = 0; k < 32; ++k) tr += W0[k][k];
  tr *= (1.f / 32.f);
  const float itr = 1.f / tr;
#pragma unroll
  for (int i = 0; i < 4; ++i) {
    int r = 4 * h + i;
    W1[r][c] = W0[r][c] * itr;
    W2[r][c] = (r == c) ? 1.f : 0.f;
  }
  __syncthreads();
  LdsMat Y = W1, Z = W2, Ya = W0, Za = W4;
  ns_sqrt(Y, Z, Ya, Za, W3, tid);
  const float rs = rsqrtf(tr);
#pragma unroll
  for (int i = 0; i < 4; ++i) { int r = 4 * h + i; wsf[OFF_INVS + r * 32 + c] = Z[r][c] * rs; }
  __syncthreads();
  float tr2 = 0.f;
#pragma unroll
  for (int k = 0; k < 32; ++k) tr2 += shift[33 * k];
  tr2 *= (1.f / 32.f);
  const float itr2 = 1.f / tr2;
#pragma unroll
  for (int i = 0; i < 4; ++i) {
    int r = 4 * h + i;
    W1[r][c] = shift[r * 32 + c] * itr2;
    W2[r][c] = (r == c) ? 1.f : 0.f;
  }
  __syncthreads();
  LdsMat Y2 = W1, Z2 = W2, Ya2 = W0, Za2 = W4;
  ns_sqrt(Y2, Z2, Ya2, Za2, W3, tid);
  const float sq2 = sqrtf(tr2);
#pragma unroll
  for (int i = 0; i < 4; ++i) { int r = 4 * h + i; wsf[OFF_SSQRT + r * 32 + c] = Y2[r][c] * sq2; }
}

// BN whiten: L_b -> d_out (scratch); var += ||L_b||_F^2   [register-only, 2-ILP, sign-alt]
extern "C" __global__ void __launch_bounds__(64, 2)
spdbn_kC(const float* __restrict__ x, float* __restrict__ wsf, float* __restrict__ outL) {
  const int lane = threadIdx.x, q = lane >> 5, n = lane & 31;
  short8 S_h[2], S_l[2];
  load_sym_frags32(wsf + OFF_INVS, n, q, S_h, S_l);
  float cof[NCHEB];
#pragma unroll
  for (int k = 0; k < NCHEB; ++k) {
    float sg = ((k >> 1) & 1) ? -1.f : 1.f;
    cof[k] = wsf[OFF_CHEB + k] * sg;
  }
  float ss = 0.f;
  f32x16 L0, L1;
  for (int b = blockIdx.x; b < BATCH / 2; b += gridDim.x) {
    whiten_cheb32_x2<false>(x + (size_t)b * 1024, x + (size_t)(b + BATCH / 2) * 1024,
                            S_h, S_l, cof, q, n, L0, L1);
    float* ob0 = outL + (size_t)b * 1024;
    float* ob1 = outL + (size_t)(b + BATCH / 2) * 1024;
#pragma unroll
    for (int rr = 0; rr < 16; ++rr) {
      int off = ((rr & 3) + 8 * (rr >> 2) + 4 * q) * 32 + n;
      float v0 = L0[rr], v1 = L1[rr];
      ob0[off] = v0;
      ob1[off] = v1;
      ss = fmaf(v0, v0, ss);
      ss = fmaf(v1, v1, ss);
    }
  }
#pragma unroll
  for (int off = 32; off >= 1; off >>= 1) ss += __shfl_xor(ss, off);
  if (lane == 0) atomicAdd(&wsf[OFF_VAR], ss);
}

extern "C" __global__ void spdbn_kS3(float* __restrict__ wsf, const float* __restrict__ scale) {
  if (threadIdx.x == 0) {
    float var = wsf[OFF_VAR] * (1.f / (float)BATCH);
    float stdv = sqrtf(var);
    wsf[OFF_P] = scale[0] / (stdv + 1e-5f);
  }
}

// out = s_sqrt * exp(p*L) * s_sqrt  (r9/r11-proven path, unchanged)
extern "C" __global__ void __launch_bounds__(64, 3)
spdbn_kD(float* __restrict__ out, const float* __restrict__ wsf) {
  __shared__ alignas(16) u16t Xh[32][40], Xl[32][40], Bu0[32][40], Bu1[32][40];
  const int lane = threadIdx.x;
  const int g = lane >> 4, c15 = lane & 15;
  short8 Q_h[2], Q_l[2];
  load_sym_frags(wsf + OFF_SSQRT, c15, g, Q_h, Q_l);
  const float p = wsf[OFF_P];
  const f32x4 z4 = {0.f, 0.f, 0.f, 0.f};
  f32x4 dg4;
#pragma unroll
  for (int r = 0; r < 4; ++r) dg4[r] = (4 * g + r == c15) ? 1.f : 0.f;
  uint2 idp; idp.x = pack2_rn(dg4[0], dg4[1]); idp.y = pack2_rn(dg4[2], dg4[3]);
  uint2 zp;  zp.x = 0u; zp.y = 0u;
  for (int b = blockIdx.x; b < BATCH; b += MAIN_BLOCKS) {
    float* ob = out + (size_t)b * 1024;
#pragma unroll
    for (int e = 0; e < 4; ++e) {
      int idx = e * 256 + lane * 4;
      float4 v = *reinterpret_cast<const float4*>(ob + idx);
      int row = idx >> 5, col = idx & 31;
      u32t h0, l0, h1, l1;
      split2(v.x * p, v.y * p, h0, l0);
      split2(v.z * p, v.w * p, h1, l1);
      uint2 hv; hv.x = h0; hv.y = h1;
      uint2 lv; lv.x = l0; lv.y = l1;
      *reinterpret_cast<uint2*>(&Xh[row][col]) = hv;
      *reinterpret_cast<uint2*>(&Xl[row][col]) = lv;
    }
#pragma unroll
    for (int i = 0; i < 2; ++i)
#pragma unroll
      for (int j = 0; j < 2; ++j)
        *reinterpret_cast<uint2*>(&Bu0[16 * j + c15][16 * i + 4 * g]) = (i == j) ? idp : zp;
    __syncthreads();
    short8 Mh[2], Ml[2];
#pragma unroll
    for (int t = 0; t < 2; ++t) { Mh[t] = fragr(Xh, t, c15, g); Ml[t] = fragr(Xl, t, c15, g); }
    f32x4 acc[2][2];
#pragma unroll
    for (int jj = EXP_TERMS; jj >= 2; --jj) {
      const int t = EXP_TERMS - jj;
      const u16t (*R)[40] = (t & 1) ? Bu1 : Bu0;
      u16t (*W)[40]       = (t & 1) ? Bu0 : Bu1;
#pragma unroll
      for (int j = 0; j < 2; ++j) {
        short8 Bh = fragr(R, j, c15, g);
#pragma unroll
        for (int i = 0; i < 2; ++i) {
          f32x4 a = z4;
          a = MFMA16(Ml[i], Bh, a);
          a = MFMA16(Mh[i], Bh, a);
          acc[i][j] = a;
        }
      }
      const float inv = 1.f / (float)jj;
      __syncthreads();
#pragma unroll
      for (int i = 0; i < 2; ++i)
#pragma unroll
        for (int j = 0; j < 2; ++j) {
          f32x4 v;
#pragma unroll
          for (int r = 0; r < 4; ++r)
            v[r] = fmaf(acc[i][j][r], inv, ((16 * i + 4 * g + r) == (16 * j + c15)) ? 1.f : 0.f);
          stg_single(W, 16 * j + c15, 16 * i + 4 * g, v);
        }
      __syncthreads();
    }
#pragma unroll
    for (int j = 0; j < 2; ++j) {
      short8 Bh = fragr(Bu1, j, c15, g);
#pragma unroll
      for (int i = 0; i < 2; ++i) {
        f32x4 a = z4;
        a = MFMA16(Ml[i], Bh, a);
        a = MFMA16(Mh[i], Bh, a);
        acc[i][j] = a;
      }
    }
    __syncthreads();
#pragma unroll
    for (int i = 0; i < 2; ++i)
#pragma unroll
      for (int j = 0; j < 2; ++j) {
        f32x4 v;
#pragma unroll
        for (int r = 0; r < 4; ++r)
          v[r] = acc[i][j][r] + (((16 * i + 4 * g + r) == (16 * j + c15)) ? 1.f : 0.f);
        stg_split(Xh, Xl, 16 * j + c15, 16 * i + 4 * g, v);
      }
    __syncthreads();
    short8 Ph[2], Pl[2];
#pragma unroll
    for (int t = 0; t < 2; ++t) { Ph[t] = fragr(Xh, t, c15, g); Pl[t] = fragr(Xl, t, c15, g); }
#pragma unroll
    for (int i = 0; i < 2; ++i)
#pragma unroll
      for (int j = 0; j < 2; ++j) {
        f32x4 a = z4;
        a = MFMA16(Pl[i], Q_h[j], a);
        a = MFMA16(Ph[i], Q_l[j], a);
        a = MFMA16(Ph[i], Q_h[j], a);
        acc[i][j] = a;
      }
    __syncthreads();
#pragma unroll
    for (int i = 0; i < 2; ++i)
#pragma unroll
      for (int j = 0; j < 2; ++j)
        stg_split(Bu0, Bu1, 16 * j + c15, 16 * i + 4 * g, acc[i][j]);
    __syncthreads();
#pragma unroll
    for (int j = 0; j < 2; ++j) {
      short8 Wh = fragr(Bu0, j, c15, g), Wl = fragr(Bu1, j, c15, g);
#pragma unroll
      for (int i = 0; i < 2; ++i) {
        f32x4 a = z4;
        a = MFMA16(Q_l[i], Wh, a);
        a = MFMA16(Q_h[i], Wl, a);
        a = MFMA16(Q_h[i], Wh, a);
        acc[i][j] = a;
      }
    }
#pragma unroll
    for (int i = 0; i < 2; ++i)
#pragma unroll
      for (int j = 0; j < 2; ++j)
#pragma unroll
        for (int r = 0; r < 4; ++r)
          ob[(16 * i + 4 * g + r) * 32 + 16 * j + c15] = acc[i][j][r];
    __syncthreads();
  }
}

extern "C" void kernel_launch(void* const* d_in, const int* in_sizes, int n_in,
                              void* d_out, int out_size, void* d_ws, size_t ws_size,
                              hipStream_t stream) {
  const float* x     = (const float*)d_in[0];
  const float* shift = (const float*)d_in[1];
  const float* scale = (const float*)d_in[2];
  float* out = (float*)d_out;
  float* wsf = (float*)d_ws;

  size_t zbytes = 32768;
  if (ws_size < zbytes) zbytes = ws_size;
  hipMemsetAsync(d_ws, 0, zbytes, stream);

  hipLaunchKernelGGL(spdbn_kA,  dim3(4096),    dim3(256), 0, stream, x, wsf);
  hipLaunchKernelGGL(spdbn_kS1, dim3(1),       dim3(256), 0, stream, wsf);
  hipLaunchKernelGGL(spdbn_kB,  dim3(GRID_BC), dim3(64),  0, stream, x, wsf);
  hipLaunchKernelGGL(spdbn_kS2, dim3(1),       dim3(256), 0, stream, wsf, shift);
  hipLaunchKernelGGL(spdbn_kC,  dim3(GRID_BC), dim3(64),  0, stream, x, wsf, out);
  hipLaunchKernelGGL(spdbn_kS3, dim3(1),       dim3(64),  0, stream, wsf, scale);
  hipLaunchKernelGGL(spdbn_kD,  dim3(MAIN_BLOCKS), dim3(64), 0, stream, out, wsf);
}

// Round 16
// 624.254 us; speedup vs baseline: 1.1397x; 1.0059x over previous
//
#include <hip/hip_runtime.h>
#include <cstdint>
#include <cstddef>

#define BATCH       65536
#define LDSW        36          // padded LDS row stride for tiny-kernel matrices
#define NCHEB       16          // Chebyshev terms on [CALPHA, CBETA] (validated r7/r8)
#define CALPHA      0.28f
#define CBETA       4.6f
#define NS_ITERS    4
#define EXP_TERMS   8
#define MAIN_BLOCKS 3072        // kD grid (r9/r11-proven path)
#define GRID_BC     2048        // kB/kC: 2-matrix ILP, 16 pairs/block

// ws float offsets
#define OFF_MEAN0   0
#define OFF_INVS0   1024
#define OFF_S0      2048
#define OFF_LOGAVG  3072
#define OFF_INVS    4096
#define OFF_SSQRT   5120
#define OFF_VAR     6144
#define OFF_P       6145
#define OFF_CHEB    6152

typedef float (*LdsMat)[LDSW];
typedef __attribute__((ext_vector_type(8)))  short short8;
typedef __attribute__((ext_vector_type(4)))  float f32x4;
typedef __attribute__((ext_vector_type(16))) float f32x16;
typedef unsigned short u16t;
typedef unsigned int   u32t;

#define MFMA16(a, b, c) __builtin_amdgcn_mfma_f32_16x16x32_bf16((a), (b), (c), 0, 0, 0)
#define MFMA32(a, b, c) __builtin_amdgcn_mfma_f32_32x32x16_bf16((a), (b), (c), 0, 0, 0)

// ---------------- bf16 pack / split helpers (perm-based, r4-r14-proven; cvt_pk REVERTED:
// r15 showed v_cvt_pk_bf16_f32 rounding injects biased per-step noise -> absmax 5e-2) ----------------
__device__ __forceinline__ u32t pack2_rn(float a, float b) {
  u32t ua = __float_as_uint(a) + 0x8000u;
  u32t ub = __float_as_uint(b) + 0x8000u;
  return __builtin_amdgcn_perm(ub, ua, 0x07060302u);
}
__device__ __forceinline__ void split2(float a, float b, u32t& hw, u32t& lw) {
  u32t ua = __float_as_uint(a) + 0x8000u;
  u32t ub = __float_as_uint(b) + 0x8000u;
  hw = __builtin_amdgcn_perm(ub, ua, 0x07060302u);
  float ra = a - __uint_as_float(ua & 0xFFFF0000u);
  float rb = b - __uint_as_float(ub & 0xFFFF0000u);
  lw = __builtin_amdgcn_perm(__float_as_uint(rb), __float_as_uint(ra), 0x07060302u);
}
__device__ __forceinline__ void split8regs(float4 a, float4 b, float mul, short8& hi, short8& lo) {
  u32t h0, l0, h1, l1, h2, l2, h3, l3;
  split2(a.x * mul, a.y * mul, h0, l0);
  split2(a.z * mul, a.w * mul, h1, l1);
  split2(b.x * mul, b.y * mul, h2, l2);
  split2(b.z * mul, b.w * mul, h3, l3);
  union { uint4 u; short8 s; } uh, ul;
  uh.u.x = h0; uh.u.y = h1; uh.u.z = h2; uh.u.w = h3;
  ul.u.x = l0; ul.u.y = l1; ul.u.z = l2; ul.u.w = l3;
  hi = uh.s; lo = ul.s;
}
__device__ __forceinline__ void splitf(float a, u16t& h, u16t& l) {
  unsigned u  = __float_as_uint(a);
  unsigned uh = (u + 0x8000u) & 0xFFFF0000u;
  float    r  = a - __uint_as_float(uh);
  unsigned ul = __float_as_uint(r) + 0x8000u;
  h = (u16t)(uh >> 16);
  l = (u16t)(ul >> 16);
}
// exact bf16 negation of a packed fragment (XOR sign bits)
__device__ __forceinline__ short8 neg8(short8 v) {
  union { uint4 u; short8 s; } a;
  a.s = v;
  a.u.x ^= 0x80008000u; a.u.y ^= 0x80008000u;
  a.u.z ^= 0x80008000u; a.u.w ^= 0x80008000u;
  return a.s;
}

// ---------------- 32x32 register-exchange helpers (r11-verified wiring) ----------------
// C-layout (32x32): lane = 32q + n holds D[row=(rr&3)+8(rr>>2)+4q][col=n], rr=0..15.
// B-frag (32x32x16, K-tile t): lane needs B[k=16t+8q+j][n], j=0..7.
__device__ __forceinline__ void cmaj_to_bfrag(const f32x16& v, short8& f0, short8& f1) {
  u32t w[8];
#pragma unroll
  for (int d = 0; d < 8; ++d) w[d] = pack2_rn(v[2 * d], v[2 * d + 1]);
  auto r02 = __builtin_amdgcn_permlane32_swap(w[0], w[2], false, false);
  auto r13 = __builtin_amdgcn_permlane32_swap(w[1], w[3], false, false);
  auto r46 = __builtin_amdgcn_permlane32_swap(w[4], w[6], false, false);
  auto r57 = __builtin_amdgcn_permlane32_swap(w[5], w[7], false, false);
  union { uint4 u; short8 s; } A, B;
  A.u.x = r02[0]; A.u.y = r13[0]; A.u.z = r02[1]; A.u.w = r13[1];
  B.u.x = r46[0]; B.u.y = r57[0]; B.u.z = r46[1]; B.u.w = r57[1];
  f0 = A.s; f1 = B.s;
}
__device__ __forceinline__ void cmaj_to_bfrag_split(const f32x16& v,
    short8& f0h, short8& f1h, short8& f0l, short8& f1l) {
  u32t wh[8], wl[8];
#pragma unroll
  for (int d = 0; d < 8; ++d) split2(v[2 * d], v[2 * d + 1], wh[d], wl[d]);
  {
    auto r02 = __builtin_amdgcn_permlane32_swap(wh[0], wh[2], false, false);
    auto r13 = __builtin_amdgcn_permlane32_swap(wh[1], wh[3], false, false);
    auto r46 = __builtin_amdgcn_permlane32_swap(wh[4], wh[6], false, false);
    auto r57 = __builtin_amdgcn_permlane32_swap(wh[5], wh[7], false, false);
    union { uint4 u; short8 s; } A, B;
    A.u.x = r02[0]; A.u.y = r13[0]; A.u.z = r02[1]; A.u.w = r13[1];
    B.u.x = r46[0]; B.u.y = r57[0]; B.u.z = r46[1]; B.u.w = r57[1];
    f0h = A.s; f1h = B.s;
  }
  {
    auto r02 = __builtin_amdgcn_permlane32_swap(wl[0], wl[2], false, false);
    auto r13 = __builtin_amdgcn_permlane32_swap(wl[1], wl[3], false, false);
    auto r46 = __builtin_amdgcn_permlane32_swap(wl[4], wl[6], false, false);
    auto r57 = __builtin_amdgcn_permlane32_swap(wl[5], wl[7], false, false);
    union { uint4 u; short8 s; } A, B;
    A.u.x = r02[0]; A.u.y = r13[0]; A.u.z = r02[1]; A.u.w = r13[1];
    B.u.x = r46[0]; B.u.y = r57[0]; B.u.z = r46[1]; B.u.w = r57[1];
    f0l = A.s; f1l = B.s;
  }
}
// Cold: load symmetric 32x32 f32 -> A/B frags (row n, k = 16t+8q+j)
__device__ __forceinline__ void load_sym_frags32(const float* base, int n, int q,
                                                 short8* Fh, short8* Fl) {
#pragma unroll
  for (int t = 0; t < 2; ++t) {
    const float* sp = base + n * 32 + 16 * t + 8 * q;
    short8 hh, ll;
#pragma unroll
    for (int j = 0; j < 8; ++j) {
      u16t h, l;
      splitf(sp[j], h, l);
      hh[j] = (short)h;
      ll[j] = (short)l;
    }
    Fh[t] = hh;
    Fl[t] = ll;
  }
}

// ---------------- register-only whiten + Chebyshev: 2-ILP, sign-alt, IN-PLACE P/Q ----------------
// X_k = (-1)^floor(k/2) T_k; X_k = MFMA(A_k, X_{k-1}, C=X_{k-2}) computed IN PLACE over
// X_{k-2} (dead after use) -> zero accumulator-rotation moves. A_k = -2Yt (even) / +2Yt (odd).
template <bool ACCUM>
__device__ __forceinline__ void whiten_cheb32_x2(
    const float* __restrict__ xb0, const float* __restrict__ xb1,
    const short8* S_h, const short8* S_l, const float* __restrict__ cof,
    int q, int n, f32x16& L0, f32x16& L1) {
  f32x16 z16;
#pragma unroll
  for (int rr = 0; rr < 16; ++rr) z16[rr] = 0.f;
  // 1. X A-frags direct from global (X symmetric)
  short8 X0h[2], X0l[2], X1h[2], X1l[2];
  float4 a00, b00, a01, b01, a10, b10, a11, b11;
  {
    const float* p0 = xb0 + n * 32 + 8 * q;
    const float* p1 = xb1 + n * 32 + 8 * q;
    a00 = *reinterpret_cast<const float4*>(p0);
    b00 = *reinterpret_cast<const float4*>(p0 + 4);
    a01 = *reinterpret_cast<const float4*>(p0 + 16);
    b01 = *reinterpret_cast<const float4*>(p0 + 20);
    a10 = *reinterpret_cast<const float4*>(p1);
    b10 = *reinterpret_cast<const float4*>(p1 + 4);
    a11 = *reinterpret_cast<const float4*>(p1 + 16);
    b11 = *reinterpret_cast<const float4*>(p1 + 20);
  }
  split8regs(a00, b00, 1.f, X0h[0], X0l[0]);
  split8regs(a01, b01, 1.f, X0h[1], X0l[1]);
  split8regs(a10, b10, 1.f, X1h[0], X1l[0]);
  split8regs(a11, b11, 1.f, X1h[1], X1l[1]);
  // 2. V2 = X * S
  f32x16 v20 = z16, v21 = z16;
#pragma unroll
  for (int t = 0; t < 2; ++t) {
    v20 = MFMA32(X0l[t], S_h[t], v20);
    v21 = MFMA32(X1l[t], S_h[t], v21);
    v20 = MFMA32(X0h[t], S_l[t], v20);
    v21 = MFMA32(X1h[t], S_l[t], v21);
    v20 = MFMA32(X0h[t], S_h[t], v20);
    v21 = MFMA32(X1h[t], S_h[t], v21);
  }
  // 3. V2 B-frags (split)
  short8 V0h[2], V0l[2], V1h[2], V1l[2];
  cmaj_to_bfrag_split(v20, V0h[0], V0h[1], V0l[0], V0l[1]);
  cmaj_to_bfrag_split(v21, V1h[0], V1h[1], V1l[0], V1l[1]);
  // 4. Y = S * V2
  f32x16 y0 = z16, y1 = z16;
#pragma unroll
  for (int t = 0; t < 2; ++t) {
    y0 = MFMA32(S_l[t], V0h[t], y0);
    y1 = MFMA32(S_l[t], V1h[t], y1);
    y0 = MFMA32(S_h[t], V0l[t], y0);
    y1 = MFMA32(S_h[t], V1l[t], y1);
    y0 = MFMA32(S_h[t], V0h[t], y0);
    y1 = MFMA32(S_h[t], V1h[t], y1);
  }
  // 5. T1 = GSC*Y - MSH*I ; init L, P = X0 = I, Q = X1 = T1
  const float GSC = 2.f / (CBETA - CALPHA);
  const float MSH = (CALPHA + CBETA) / (CBETA - CALPHA);
  const float c0 = cof[0], c1 = cof[1];
  f32x16 P0, Q0, P1, Q1;
#pragma unroll
  for (int rr = 0; rr < 16; ++rr) {
    int row = (rr & 3) + 8 * (rr >> 2) + 4 * q;
    float dgf = (row == n) ? 1.f : 0.f;
    float t10 = fmaf(y0[rr], GSC, -MSH * dgf);
    float t11 = fmaf(y1[rr], GSC, -MSH * dgf);
    Q0[rr] = t10;
    Q1[rr] = t11;
    P0[rr] = dgf;
    P1[rr] = dgf;
    float base0 = ACCUM ? L0[rr] : 0.f;
    float base1 = ACCUM ? L1[rr] : 0.f;
    L0[rr] = fmaf(c1, t10, fmaf(c0, dgf, base0));
    L1[rr] = fmaf(c1, t11, fmaf(c0, dgf, base1));
  }
  // A-frags of +2*Ytilde (split) and exact bf16 negation (-2*Ytilde)
  f32x16 y20, y21;
#pragma unroll
  for (int rr = 0; rr < 16; ++rr) { y20[rr] = Q0[rr] + Q0[rr]; y21[rr] = Q1[rr] + Q1[rr]; }
  short8 Y0h[2], Y0l[2], Y1h[2], Y1l[2];
  cmaj_to_bfrag_split(y20, Y0h[0], Y0h[1], Y0l[0], Y0l[1]);
  cmaj_to_bfrag_split(y21, Y1h[0], Y1h[1], Y1l[0], Y1l[1]);
  short8 N0h[2], N0l[2], N1h[2], N1l[2];
#pragma unroll
  for (int t = 0; t < 2; ++t) {
    N0h[t] = neg8(Y0h[t]); N0l[t] = neg8(Y0l[t]);
    N1h[t] = neg8(Y1h[t]); N1l[t] = neg8(Y1l[t]);
  }
  // 6. in-place ping-pong, 2 steps/iter: P = X_even, Q = X_odd (chains interleaved)
#pragma unroll
  for (int k = 2; k < NCHEB; k += 2) {
    // even step k: A = -2Yt; P(X_{k-2}) <- X_k
    {
      short8 B00, B01, B10, B11;
      cmaj_to_bfrag(Q0, B00, B01);
      cmaj_to_bfrag(Q1, B10, B11);
      P0 = MFMA32(N0l[0], B00, P0);
      P1 = MFMA32(N1l[0], B10, P1);
      P0 = MFMA32(N0h[0], B00, P0);
      P1 = MFMA32(N1h[0], B10, P1);
      P0 = MFMA32(N0l[1], B01, P0);
      P1 = MFMA32(N1l[1], B11, P1);
      P0 = MFMA32(N0h[1], B01, P0);
      P1 = MFMA32(N1h[1], B11, P1);
      const float ck = cof[k];
#pragma unroll
      for (int rr = 0; rr < 16; ++rr) {
        L0[rr] = fmaf(ck, P0[rr], L0[rr]);
        L1[rr] = fmaf(ck, P1[rr], L1[rr]);
      }
    }
    // odd step k+1: A = +2Yt; Q(X_{k-1}) <- X_{k+1}
    {
      short8 B00, B01, B10, B11;
      cmaj_to_bfrag(P0, B00, B01);
      cmaj_to_bfrag(P1, B10, B11);
      Q0 = MFMA32(Y0l[0], B00, Q0);
      Q1 = MFMA32(Y1l[0], B10, Q1);
      Q0 = MFMA32(Y0h[0], B00, Q0);
      Q1 = MFMA32(Y1h[0], B10, Q1);
      Q0 = MFMA32(Y0l[1], B01, Q0);
      Q1 = MFMA32(Y1l[1], B11, Q1);
      Q0 = MFMA32(Y0h[1], B01, Q0);
      Q1 = MFMA32(Y1h[1], B11, Q1);
      const float ck = cof[k + 1];
#pragma unroll
      for (int rr = 0; rr < 16; ++rr) {
        L0[rr] = fmaf(ck, Q0[rr], L0[rr]);
        L1[rr] = fmaf(ck, Q1[rr], L1[rr]);
      }
    }
  }
}

// ---------------- 16x16 LDS helpers (kD path, r9-proven, unchanged) ----------------
__device__ __forceinline__ short8 fragr(const u16t (*G)[40], int t, int c15, int g) {
  return *reinterpret_cast<const short8*>(&G[16 * t + c15][8 * g]);
}
__device__ __forceinline__ void stg_single(u16t (*G)[40], int col, int row, f32x4 v) {
  uint2 w; w.x = pack2_rn(v[0], v[1]); w.y = pack2_rn(v[2], v[3]);
  *reinterpret_cast<uint2*>(&G[col][row]) = w;
}
__device__ __forceinline__ void stg_split(u16t (*Gh)[40], u16t (*Gl)[40], int col, int row, f32x4 v) {
  u32t h0, l0, h1, l1;
  split2(v[0], v[1], h0, l0);
  split2(v[2], v[3], h1, l1);
  uint2 hv; hv.x = h0; hv.y = h1;
  uint2 lv; lv.x = l0; lv.y = l1;
  *reinterpret_cast<uint2*>(&Gh[col][row]) = hv;
  *reinterpret_cast<uint2*>(&Gl[col][row]) = lv;
}
__device__ __forceinline__ void load_sym_frags(const float* base, int c15, int g,
                                               short8* Fh, short8* Fl) {
#pragma unroll
  for (int t = 0; t < 2; ++t) {
    const float* sp = base + (16 * t + c15) * 32 + 8 * g;
    short8 hh, ll;
#pragma unroll
    for (int j = 0; j < 8; ++j) {
      u16t h, l;
      splitf(sp[j], h, l);
      hh[j] = (short)h;
      ll[j] = (short)l;
    }
    Fh[t] = hh;
    Fl[t] = ll;
  }
}

// ---------- tiny-kernel helpers (single block, 256 threads; r9-proven) ----------
__device__ __forceinline__ float dotrow36(const float* Arow, const float* v) {
  float s = 0.f;
#pragma unroll
  for (int j = 0; j < 8; ++j) {
    float4 a = *reinterpret_cast<const float4*>(Arow + 4 * j);
    s = fmaf(a.x, v[4 * j + 0], s);
    s = fmaf(a.y, v[4 * j + 1], s);
    s = fmaf(a.z, v[4 * j + 2], s);
    s = fmaf(a.w, v[4 * j + 3], s);
  }
  return s;
}
__device__ void mm64(float (*D)[LDSW], const float (*A)[LDSW], const float (*Bm)[LDSW], int tid) {
  const int h = tid >> 5, c = tid & 31;
  float bcol[32];
#pragma unroll
  for (int k = 0; k < 32; ++k) bcol[k] = Bm[k][c];
  float o[4];
#pragma unroll
  for (int i = 0; i < 4; ++i) o[i] = dotrow36(&A[4 * h + i][0], bcol);
  __syncthreads();
#pragma unroll
  for (int i = 0; i < 4; ++i) D[4 * h + i][c] = o[i];
  __syncthreads();
}
__device__ void ns_sqrt(LdsMat& Y, LdsMat& Z, LdsMat& Ya, LdsMat& Za, LdsMat T, int tid) {
  const int h = tid >> 5, c = tid & 31;
  for (int it = 0; it < NS_ITERS; ++it) {
    mm64(T, Z, Y, tid);
#pragma unroll
    for (int i = 0; i < 4; ++i) {
      int r = 4 * h + i;
      T[r][c] = ((r == c) ? 1.5f : 0.f) - 0.5f * T[r][c];
    }
    __syncthreads();
    mm64(Ya, Y, T, tid);
    mm64(Za, T, Z, tid);
    LdsMat t1 = Y; Y = Ya; Ya = t1;
    LdsMat t2 = Z; Z = Za; Za = t2;
  }
}

// ---------- kernels ----------

extern "C" __global__ void __launch_bounds__(256)
spdbn_kA(const float* __restrict__ x, float* __restrict__ wsf) {
  const int e  = (blockIdx.x & 3) * 256 + threadIdx.x;
  const int bs = blockIdx.x >> 2;
  float acc = 0.f;
  for (int t = 0; t < 64; ++t)
    acc += x[(size_t)(bs + 1024 * t) * 1024 + e];
  atomicAdd(&wsf[OFF_MEAN0 + e], acc);
}

extern "C" __global__ void __launch_bounds__(256)
spdbn_kS1(float* __restrict__ wsf) {
  __shared__ alignas(16) float W0[32][LDSW], W1[32][LDSW], W2[32][LDSW], W3[32][LDSW], W4[32][LDSW];
  const int tid = threadIdx.x, h = tid >> 5, c = tid & 31;
  float sacc = 0.f;
#pragma unroll
  for (int k = 0; k < 32; ++k) sacc += wsf[OFF_MEAN0 + 33 * k];
  const float cN = sacc / (32.f * (float)BATCH);
  const float scaleA = 32.f / sacc;
#pragma unroll
  for (int i = 0; i < 4; ++i) {
    int r = 4 * h + i;
    W1[r][c] = wsf[OFF_MEAN0 + r * 32 + c] * scaleA;
    W2[r][c] = (r == c) ? 1.f : 0.f;
  }
  __syncthreads();
  LdsMat Y = W1, Z = W2, Ya = W0, Za = W4;
  ns_sqrt(Y, Z, Ya, Za, W3, tid);
  const float sq = sqrtf(cN), rs = rsqrtf(cN);
#pragma unroll
  for (int i = 0; i < 4; ++i) {
    int r = 4 * h + i;
    wsf[OFF_INVS0 + r * 32 + c] = Z[r][c] * rs;
    wsf[OFF_S0    + r * 32 + c] = Y[r][c] * sq;
  }
  if (tid < 64) {
    const float PIF = 3.14159265358979f;
    const float th = ((float)tid + 0.5f) * (PIF / 64.f);
    const float t  = 0.5f * (CALPHA + CBETA) + 0.5f * (CBETA - CALPHA) * cosf(th);
    const float fl = logf(t);
    for (int j = 0; j < NCHEB; ++j) {
      float v = fl * cosf((float)j * th) * (2.f / 64.f);
#pragma unroll
      for (int off = 32; off >= 1; off >>= 1) v += __shfl_xor(v, off);
      if (tid == 0) wsf[OFF_CHEB + j] = (j == 0) ? 0.5f * v : v;
    }
  }
}

// Karcher step: accumulate sum_b log(inv_s0 x_b inv_s0)   [register-only, 2-ILP, in-place]
extern "C" __global__ void __launch_bounds__(64, 2)
spdbn_kB(const float* __restrict__ x, float* __restrict__ wsf) {
  const int lane = threadIdx.x, q = lane >> 5, n = lane & 31;
  short8 S_h[2], S_l[2];
  load_sym_frags32(wsf + OFF_INVS0, n, q, S_h, S_l);
  float cof[NCHEB];
#pragma unroll
  for (int k = 0; k < NCHEB; ++k) {
    float sg = ((k >> 1) & 1) ? -1.f : 1.f;   // fold (-1)^floor(k/2) into coeffs
    cof[k] = wsf[OFF_CHEB + k] * sg;
  }
  f32x16 L0, L1;
#pragma unroll
  for (int rr = 0; rr < 16; ++rr) { L0[rr] = 0.f; L1[rr] = 0.f; }
  for (int b = blockIdx.x; b < BATCH / 2; b += gridDim.x)
    whiten_cheb32_x2<true>(x + (size_t)b * 1024, x + (size_t)(b + BATCH / 2) * 1024,
                           S_h, S_l, cof, q, n, L0, L1);
#pragma unroll
  for (int rr = 0; rr < 16; ++rr)
    atomicAdd(&wsf[OFF_LOGAVG + ((rr & 3) + 8 * (rr >> 2) + 4 * q) * 32 + n], L0[rr] + L1[rr]);
}

extern "C" __global__ void __launch_bounds__(256)
spdbn_kS2(float* __restrict__ wsf, const float* __restrict__ shift) {
  __shared__ alignas(16) float W0[32][LDSW], W1[32][LDSW], W2[32][LDSW], W3[32][LDSW], W4[32][LDSW];
  const int tid = threadIdx.x, h = tid >> 5, c = tid & 31;
#pragma unroll
  for (int i = 0; i < 4; ++i) {
    int r = 4 * h + i;
    W0[r][c] = wsf[OFF_LOGAVG + r * 32 + c] * (1.f / (float)BATCH);
    W1[r][c] = (r == c) ? 1.f : 0.f;
  }
  __syncthreads();
  for (int j = EXP_TERMS; j >= 1; --j) {
    mm64(W3, W0, W1, tid);
    const float inv = 1.f / (float)j;
#pragma unroll
    for (int i = 0; i < 4; ++i) {
      int r = 4 * h + i;
      W1[r][c] = ((r == c) ? 1.f : 0.f) + W3[r][c] * inv;
    }
    __syncthreads();
  }
#pragma unroll
  for (int i = 0; i < 4; ++i) { int r = 4 * h + i; W2[r][c] = wsf[OFF_S0 + r * 32 + c]; }
  __syncthreads();
  mm64(W3, W2, W1, tid);
  mm64(W0, W3, W2, tid);
  float tr = 0.f;
#pragma unroll
  for (int k = 0; k < 32; ++k) tr += W0[k][k];
  tr *= (1.f / 32.f);
  const float itr = 1.f / tr;
#pragma unroll
  for (int i = 0; i < 4; ++i) {
    int r = 4 * h + i;
    W1[r][c] = W0[r][c] * itr;
    W2[r][c] = (r == c) ? 1.f : 0.f;
  }
  __syncthreads();
  LdsMat Y = W1, Z = W2, Ya = W0, Za = W4;
  ns_sqrt(Y, Z, Ya, Za, W3, tid);
  const float rs = rsqrtf(tr);
#pragma unroll
  for (int i = 0; i < 4; ++i) { int r = 4 * h + i; wsf[OFF_INVS + r * 32 + c] = Z[r][c] * rs; }
  __syncthreads();
  float tr2 = 0.f;
#pragma unroll
  for (int k = 0; k < 32; ++k) tr2 += shift[33 * k];
  tr2 *= (1.f / 32.f);
  const float itr2 = 1.f / tr2;
#pragma unroll
  for (int i = 0; i < 4; ++i) {
    int r = 4 * h + i;
    W1[r][c] = shift[r * 32 + c] * itr2;
    W2[r][c] = (r == c) ? 1.f : 0.f;
  }
  __syncthreads();
  LdsMat Y2 = W1, Z2 = W2, Ya2 = W0, Za2 = W4;
  ns_sqrt(Y2, Z2, Ya2, Za2, W3, tid);
  const float sq2 = sqrtf(tr2);
#pragma unroll
  for (int i = 0; i < 4; ++i) { int r = 4 * h + i; wsf[OFF_SSQRT + r * 32 + c] = Y2[r][c] * sq2; }
}

// BN whiten: L_b -> d_out (scratch); var += ||L_b||_F^2   [register-only, 2-ILP, in-place]
extern "C" __global__ void __launch_bounds__(64, 2)
spdbn_kC(const float* __restrict__ x, float* __restrict__ wsf, float* __restrict__ outL) {
  const int lane = threadIdx.x, q = lane >> 5, n = lane & 31;
  short8 S_h[2], S_l[2];
  load_sym_frags32(wsf + OFF_INVS, n, q, S_h, S_l);
  float cof[NCHEB];
#pragma unroll
  for (int k = 0; k < NCHEB; ++k) {
    float sg = ((k >> 1) & 1) ? -1.f : 1.f;
    cof[k] = wsf[OFF_CHEB + k] * sg;
  }
  float ss = 0.f;
  f32x16 L0, L1;
  for (int b = blockIdx.x; b < BATCH / 2; b += gridDim.x) {
    whiten_cheb32_x2<false>(x + (size_t)b * 1024, x + (size_t)(b + BATCH / 2) * 1024,
                            S_h, S_l, cof, q, n, L0, L1);
    float* ob0 = outL + (size_t)b * 1024;
    float* ob1 = outL + (size_t)(b + BATCH / 2) * 1024;
#pragma unroll
    for (int rr = 0; rr < 16; ++rr) {
      int off = ((rr & 3) + 8 * (rr >> 2) + 4 * q) * 32 + n;
      float v0 = L0[rr], v1 = L1[rr];
      ob0[off] = v0;
      ob1[off] = v1;
      ss = fmaf(v0, v0, ss);
      ss = fmaf(v1, v1, ss);
    }
  }
#pragma unroll
  for (int off = 32; off >= 1; off >>= 1) ss += __shfl_xor(ss, off);
  if (lane == 0) atomicAdd(&wsf[OFF_VAR], ss);
}

extern "C" __global__ void spdbn_kS3(float* __restrict__ wsf, const float* __restrict__ scale) {
  if (threadIdx.x == 0) {
    float var = wsf[OFF_VAR] * (1.f / (float)BATCH);
    float stdv = sqrtf(var);
    wsf[OFF_P] = scale[0] / (stdv + 1e-5f);
  }
}

// out = s_sqrt * exp(p*L) * s_sqrt  (r9/r11-proven path, unchanged)
extern "C" __global__ void __launch_bounds__(64, 3)
spdbn_kD(float* __restrict__ out, const float* __restrict__ wsf) {
  __shared__ alignas(16) u16t Xh[32][40], Xl[32][40], Bu0[32][40], Bu1[32][40];
  const int lane = threadIdx.x;
  const int g = lane >> 4, c15 = lane & 15;
  short8 Q_h[2], Q_l[2];
  load_sym_frags(wsf + OFF_SSQRT, c15, g, Q_h, Q_l);
  const float p = wsf[OFF_P];
  const f32x4 z4 = {0.f, 0.f, 0.f, 0.f};
  f32x4 dg4;
#pragma unroll
  for (int r = 0; r < 4; ++r) dg4[r] = (4 * g + r == c15) ? 1.f : 0.f;
  uint2 idp; idp.x = pack2_rn(dg4[0], dg4[1]); idp.y = pack2_rn(dg4[2], dg4[3]);
  uint2 zp;  zp.x = 0u; zp.y = 0u;
  for (int b = blockIdx.x; b < BATCH; b += MAIN_BLOCKS) {
    float* ob = out + (size_t)b * 1024;
#pragma unroll
    for (int e = 0; e < 4; ++e) {
      int idx = e * 256 + lane * 4;
      float4 v = *reinterpret_cast<const float4*>(ob + idx);
      int row = idx >> 5, col = idx & 31;
      u32t h0, l0, h1, l1;
      split2(v.x * p, v.y * p, h0, l0);
      split2(v.z * p, v.w * p, h1, l1);
      uint2 hv; hv.x = h0; hv.y = h1;
      uint2 lv; lv.x = l0; lv.y = l1;
      *reinterpret_cast<uint2*>(&Xh[row][col]) = hv;
      *reinterpret_cast<uint2*>(&Xl[row][col]) = lv;
    }
#pragma unroll
    for (int i = 0; i < 2; ++i)
#pragma unroll
      for (int j = 0; j < 2; ++j)
        *reinterpret_cast<uint2*>(&Bu0[16 * j + c15][16 * i + 4 * g]) = (i == j) ? idp : zp;
    __syncthreads();
    short8 Mh[2], Ml[2];
#pragma unroll
    for (int t = 0; t < 2; ++t) { Mh[t] = fragr(Xh, t, c15, g); Ml[t] = fragr(Xl, t, c15, g); }
    f32x4 acc[2][2];
#pragma unroll
    for (int jj = EXP_TERMS; jj >= 2; --jj) {
      const int t = EXP_TERMS - jj;
      const u16t (*R)[40] = (t & 1) ? Bu1 : Bu0;
      u16t (*W)[40]       = (t & 1) ? Bu0 : Bu1;
#pragma unroll
      for (int j = 0; j < 2; ++j) {
        short8 Bh = fragr(R, j, c15, g);
#pragma unroll
        for (int i = 0; i < 2; ++i) {
          f32x4 a = z4;
          a = MFMA16(Ml[i], Bh, a);
          a = MFMA16(Mh[i], Bh, a);
          acc[i][j] = a;
        }
      }
      const float inv = 1.f / (float)jj;
      __syncthreads();
#pragma unroll
      for (int i = 0; i < 2; ++i)
#pragma unroll
        for (int j = 0; j < 2; ++j) {
          f32x4 v;
#pragma unroll
          for (int r = 0; r < 4; ++r)
            v[r] = fmaf(acc[i][j][r], inv, ((16 * i + 4 * g + r) == (16 * j + c15)) ? 1.f : 0.f);
          stg_single(W, 16 * j + c15, 16 * i + 4 * g, v);
        }
      __syncthreads();
    }
#pragma unroll
    for (int j = 0; j < 2; ++j) {
      short8 Bh = fragr(Bu1, j, c15, g);
#pragma unroll
      for (int i = 0; i < 2; ++i) {
        f32x4 a = z4;
        a = MFMA16(Ml[i], Bh, a);
        a = MFMA16(Mh[i], Bh, a);
        acc[i][j] = a;
      }
    }
    __syncthreads();
#pragma unroll
    for (int i = 0; i < 2; ++i)
#pragma unroll
      for (int j = 0; j < 2; ++j) {
        f32x4 v;
#pragma unroll
        for (int r = 0; r < 4; ++r)
          v[r] = acc[i][j][r] + (((16 * i + 4 * g + r) == (16 * j + c15)) ? 1.f : 0.f);
        stg_split(Xh, Xl, 16 * j + c15, 16 * i + 4 * g, v);
      }
    __syncthreads();
    short8 Ph[2], Pl[2];
#pragma unroll
    for (int t = 0; t < 2; ++t) { Ph[t] = fragr(Xh, t, c15, g); Pl[t] = fragr(Xl, t, c15, g); }
#pragma unroll
    for (int i = 0; i < 2; ++i)
#pragma unroll
      for (int j = 0; j < 2; ++j) {
        f32x4 a = z4;
        a = MFMA16(Pl[i], Q_h[j], a);
        a = MFMA16(Ph[i], Q_l[j], a);
        a = MFMA16(Ph[i], Q_h[j], a);
        acc[i][j] = a;
      }
    __syncthreads();
#pragma unroll
    for (int i = 0; i < 2; ++i)
#pragma unroll
      for (int j = 0; j < 2; ++j)
        stg_split(Bu0, Bu1, 16 * j + c15, 16 * i + 4 * g, acc[i][j]);
    __syncthreads();
#pragma unroll
    for (int j = 0; j < 2; ++j) {
      short8 Wh = fragr(Bu0, j, c15, g), Wl = fragr(Bu1, j, c15, g);
#pragma unroll
      for (int i = 0; i < 2; ++i) {
        f32x4 a = z4;
        a = MFMA16(Q_l[i], Wh, a);
        a = MFMA16(Q_h[i], Wl, a);
        a = MFMA16(Q_h[i], Wh, a);
        acc[i][j] = a;
      }
    }
#pragma unroll
    for (int i = 0; i < 2; ++i)
#pragma unroll
      for (int j = 0; j < 2; ++j)
#pragma unroll
        for (int r = 0; r < 4; ++r)
          ob[(16 * i + 4 * g + r) * 32 + 16 * j + c15] = acc[i][j][r];
    __syncthreads();
  }
}

extern "C" void kernel_launch(void* const* d_in, const int* in_sizes, int n_in,
                              void* d_out, int out_size, void* d_ws, size_t ws_size,
                              hipStream_t stream) {
  const float* x     = (const float*)d_in[0];
  const float* shift = (const float*)d_in[1];
  const float* scale = (const float*)d_in[2];
  float* out = (float*)d_out;
  float* wsf = (float*)d_ws;

  size_t zbytes = 32768;
  if (ws_size < zbytes) zbytes = ws_size;
  hipMemsetAsync(d_ws, 0, zbytes, stream);

  hipLaunchKernelGGL(spdbn_kA,  dim3(4096),    dim3(256), 0, stream, x, wsf);
  hipLaunchKernelGGL(spdbn_kS1, dim3(1),       dim3(256), 0, stream, wsf);
  hipLaunchKernelGGL(spdbn_kB,  dim3(GRID_BC), dim3(64),  0, stream, x, wsf);
  hipLaunchKernelGGL(spdbn_kS2, dim3(1),       dim3(256), 0, stream, wsf, shift);
  hipLaunchKernelGGL(spdbn_kC,  dim3(GRID_BC), dim3(64),  0, stream, x, wsf, out);
  hipLaunchKernelGGL(spdbn_kS3, dim3(1),       dim3(64),  0, stream, wsf, scale);
  hipLaunchKernelGGL(spdbn_kD,  dim3(MAIN_BLOCKS), dim3(64), 0, stream, out, wsf);
}

// Round 17
// 562.253 us; speedup vs baseline: 1.2654x; 1.1103x over previous
//
#include <hip/hip_runtime.h>
#include <cstdint>
#include <cstddef>

#define BATCH       65536
#define LDSW        36          // padded LDS row stride for tiny-kernel matrices
#define NCHEB       12          // Chebyshev terms on [CALPHA, CBETA]; tail = 2u^12/(12(1-u)) ~ 1e-3
#define CALPHA      0.28f
#define CBETA       4.6f
#define NS_ITERS    4
#define EXP_TERMS   8
#define MAIN_BLOCKS 3072        // kD grid (r9/r11-proven path)
#define GRID_BC     2048        // kB/kC: 2-matrix ILP, 16 pairs/block

// ws float offsets
#define OFF_MEAN0   0
#define OFF_INVS0   1024
#define OFF_S0      2048
#define OFF_LOGAVG  3072
#define OFF_INVS    4096
#define OFF_SSQRT   5120
#define OFF_VAR     6144
#define OFF_P       6145
#define OFF_CHEB    6152

typedef float (*LdsMat)[LDSW];
typedef __attribute__((ext_vector_type(8)))  short short8;
typedef __attribute__((ext_vector_type(4)))  float f32x4;
typedef __attribute__((ext_vector_type(16))) float f32x16;
typedef unsigned short u16t;
typedef unsigned int   u32t;

#define MFMA16(a, b, c) __builtin_amdgcn_mfma_f32_16x16x32_bf16((a), (b), (c), 0, 0, 0)
#define MFMA32(a, b, c) __builtin_amdgcn_mfma_f32_32x32x16_bf16((a), (b), (c), 0, 0, 0)

// ---------------- bf16 pack / split helpers (perm-based, r4-r14-proven) ----------------
__device__ __forceinline__ u32t pack2_rn(float a, float b) {
  u32t ua = __float_as_uint(a) + 0x8000u;
  u32t ub = __float_as_uint(b) + 0x8000u;
  return __builtin_amdgcn_perm(ub, ua, 0x07060302u);
}
__device__ __forceinline__ void split2(float a, float b, u32t& hw, u32t& lw) {
  u32t ua = __float_as_uint(a) + 0x8000u;
  u32t ub = __float_as_uint(b) + 0x8000u;
  hw = __builtin_amdgcn_perm(ub, ua, 0x07060302u);
  float ra = a - __uint_as_float(ua & 0xFFFF0000u);
  float rb = b - __uint_as_float(ub & 0xFFFF0000u);
  lw = __builtin_amdgcn_perm(__float_as_uint(rb), __float_as_uint(ra), 0x07060302u);
}
__device__ __forceinline__ void split8regs(float4 a, float4 b, float mul, short8& hi, short8& lo) {
  u32t h0, l0, h1, l1, h2, l2, h3, l3;
  split2(a.x * mul, a.y * mul, h0, l0);
  split2(a.z * mul, a.w * mul, h1, l1);
  split2(b.x * mul, b.y * mul, h2, l2);
  split2(b.z * mul, b.w * mul, h3, l3);
  union { uint4 u; short8 s; } uh, ul;
  uh.u.x = h0; uh.u.y = h1; uh.u.z = h2; uh.u.w = h3;
  ul.u.x = l0; ul.u.y = l1; ul.u.z = l2; ul.u.w = l3;
  hi = uh.s; lo = ul.s;
}
__device__ __forceinline__ void splitf(float a, u16t& h, u16t& l) {
  unsigned u  = __float_as_uint(a);
  unsigned uh = (u + 0x8000u) & 0xFFFF0000u;
  float    r  = a - __uint_as_float(uh);
  unsigned ul = __float_as_uint(r) + 0x8000u;
  h = (u16t)(uh >> 16);
  l = (u16t)(ul >> 16);
}
// exact bf16 negation of a packed fragment (XOR sign bits)
__device__ __forceinline__ short8 neg8(short8 v) {
  union { uint4 u; short8 s; } a;
  a.s = v;
  a.u.x ^= 0x80008000u; a.u.y ^= 0x80008000u;
  a.u.z ^= 0x80008000u; a.u.w ^= 0x80008000u;
  return a.s;
}

// ---------------- 32x32 register-exchange helpers (r11-verified wiring) ----------------
// C-layout (32x32): lane = 32q + n holds D[row=(rr&3)+8(rr>>2)+4q][col=n], rr=0..15.
// B-frag (32x32x16, K-tile t): lane needs B[k=16t+8q+j][n], j=0..7.
__device__ __forceinline__ void cmaj_to_bfrag(const f32x16& v, short8& f0, short8& f1) {
  u32t w[8];
#pragma unroll
  for (int d = 0; d < 8; ++d) w[d] = pack2_rn(v[2 * d], v[2 * d + 1]);
  auto r02 = __builtin_amdgcn_permlane32_swap(w[0], w[2], false, false);
  auto r13 = __builtin_amdgcn_permlane32_swap(w[1], w[3], false, false);
  auto r46 = __builtin_amdgcn_permlane32_swap(w[4], w[6], false, false);
  auto r57 = __builtin_amdgcn_permlane32_swap(w[5], w[7], false, false);
  union { uint4 u; short8 s; } A, B;
  A.u.x = r02[0]; A.u.y = r13[0]; A.u.z = r02[1]; A.u.w = r13[1];
  B.u.x = r46[0]; B.u.y = r57[0]; B.u.z = r46[1]; B.u.w = r57[1];
  f0 = A.s; f1 = B.s;
}
__device__ __forceinline__ void cmaj_to_bfrag_split(const f32x16& v,
    short8& f0h, short8& f1h, short8& f0l, short8& f1l) {
  u32t wh[8], wl[8];
#pragma unroll
  for (int d = 0; d < 8; ++d) split2(v[2 * d], v[2 * d + 1], wh[d], wl[d]);
  {
    auto r02 = __builtin_amdgcn_permlane32_swap(wh[0], wh[2], false, false);
    auto r13 = __builtin_amdgcn_permlane32_swap(wh[1], wh[3], false, false);
    auto r46 = __builtin_amdgcn_permlane32_swap(wh[4], wh[6], false, false);
    auto r57 = __builtin_amdgcn_permlane32_swap(wh[5], wh[7], false, false);
    union { uint4 u; short8 s; } A, B;
    A.u.x = r02[0]; A.u.y = r13[0]; A.u.z = r02[1]; A.u.w = r13[1];
    B.u.x = r46[0]; B.u.y = r57[0]; B.u.z = r46[1]; B.u.w = r57[1];
    f0h = A.s; f1h = B.s;
  }
  {
    auto r02 = __builtin_amdgcn_permlane32_swap(wl[0], wl[2], false, false);
    auto r13 = __builtin_amdgcn_permlane32_swap(wl[1], wl[3], false, false);
    auto r46 = __builtin_amdgcn_permlane32_swap(wl[4], wl[6], false, false);
    auto r57 = __builtin_amdgcn_permlane32_swap(wl[5], wl[7], false, false);
    union { uint4 u; short8 s; } A, B;
    A.u.x = r02[0]; A.u.y = r13[0]; A.u.z = r02[1]; A.u.w = r13[1];
    B.u.x = r46[0]; B.u.y = r57[0]; B.u.z = r46[1]; B.u.w = r57[1];
    f0l = A.s; f1l = B.s;
  }
}
// Cold: load symmetric 32x32 f32 -> A/B frags (row n, k = 16t+8q+j)
__device__ __forceinline__ void load_sym_frags32(const float* base, int n, int q,
                                                 short8* Fh, short8* Fl) {
#pragma unroll
  for (int t = 0; t < 2; ++t) {
    const float* sp = base + n * 32 + 16 * t + 8 * q;
    short8 hh, ll;
#pragma unroll
    for (int j = 0; j < 8; ++j) {
      u16t h, l;
      splitf(sp[j], h, l);
      hh[j] = (short)h;
      ll[j] = (short)l;
    }
    Fh[t] = hh;
    Fl[t] = ll;
  }
}

// ---------------- register-only whiten + Chebyshev: 2-ILP, sign-alt, in-place P/Q ----------------
// X_k = (-1)^floor(k/2) T_k; X_k = MFMA(A_k, X_{k-1}, C=X_{k-2}) in place over X_{k-2}.
// A_k = -2Yt (k even) / +2Yt (k odd); cof[] pre-sign-folded.
template <bool ACCUM>
__device__ __forceinline__ void whiten_cheb32_x2(
    const float* __restrict__ xb0, const float* __restrict__ xb1,
    const short8* S_h, const short8* S_l, const float* __restrict__ cof,
    int q, int n, f32x16& L0, f32x16& L1) {
  f32x16 z16;
#pragma unroll
  for (int rr = 0; rr < 16; ++rr) z16[rr] = 0.f;
  // 1. X A-frags direct from global (X symmetric)
  short8 X0h[2], X0l[2], X1h[2], X1l[2];
  float4 a00, b00, a01, b01, a10, b10, a11, b11;
  {
    const float* p0 = xb0 + n * 32 + 8 * q;
    const float* p1 = xb1 + n * 32 + 8 * q;
    a00 = *reinterpret_cast<const float4*>(p0);
    b00 = *reinterpret_cast<const float4*>(p0 + 4);
    a01 = *reinterpret_cast<const float4*>(p0 + 16);
    b01 = *reinterpret_cast<const float4*>(p0 + 20);
    a10 = *reinterpret_cast<const float4*>(p1);
    b10 = *reinterpret_cast<const float4*>(p1 + 4);
    a11 = *reinterpret_cast<const float4*>(p1 + 16);
    b11 = *reinterpret_cast<const float4*>(p1 + 20);
  }
  split8regs(a00, b00, 1.f, X0h[0], X0l[0]);
  split8regs(a01, b01, 1.f, X0h[1], X0l[1]);
  split8regs(a10, b10, 1.f, X1h[0], X1l[0]);
  split8regs(a11, b11, 1.f, X1h[1], X1l[1]);
  // 2. V2 = X * S
  f32x16 v20 = z16, v21 = z16;
#pragma unroll
  for (int t = 0; t < 2; ++t) {
    v20 = MFMA32(X0l[t], S_h[t], v20);
    v21 = MFMA32(X1l[t], S_h[t], v21);
    v20 = MFMA32(X0h[t], S_l[t], v20);
    v21 = MFMA32(X1h[t], S_l[t], v21);
    v20 = MFMA32(X0h[t], S_h[t], v20);
    v21 = MFMA32(X1h[t], S_h[t], v21);
  }
  // 3. V2 B-frags (split)
  short8 V0h[2], V0l[2], V1h[2], V1l[2];
  cmaj_to_bfrag_split(v20, V0h[0], V0h[1], V0l[0], V0l[1]);
  cmaj_to_bfrag_split(v21, V1h[0], V1h[1], V1l[0], V1l[1]);
  // 4. Y = S * V2
  f32x16 y0 = z16, y1 = z16;
#pragma unroll
  for (int t = 0; t < 2; ++t) {
    y0 = MFMA32(S_l[t], V0h[t], y0);
    y1 = MFMA32(S_l[t], V1h[t], y1);
    y0 = MFMA32(S_h[t], V0l[t], y0);
    y1 = MFMA32(S_h[t], V1l[t], y1);
    y0 = MFMA32(S_h[t], V0h[t], y0);
    y1 = MFMA32(S_h[t], V1h[t], y1);
  }
  // 5. T1 = GSC*Y - MSH*I ; init L, P = X0 = I, Q = X1 = T1
  const float GSC = 2.f / (CBETA - CALPHA);
  const float MSH = (CALPHA + CBETA) / (CBETA - CALPHA);
  const float c0 = cof[0], c1 = cof[1];
  f32x16 P0, Q0, P1, Q1;
#pragma unroll
  for (int rr = 0; rr < 16; ++rr) {
    int row = (rr & 3) + 8 * (rr >> 2) + 4 * q;
    float dgf = (row == n) ? 1.f : 0.f;
    float t10 = fmaf(y0[rr], GSC, -MSH * dgf);
    float t11 = fmaf(y1[rr], GSC, -MSH * dgf);
    Q0[rr] = t10;
    Q1[rr] = t11;
    P0[rr] = dgf;
    P1[rr] = dgf;
    float base0 = ACCUM ? L0[rr] : 0.f;
    float base1 = ACCUM ? L1[rr] : 0.f;
    L0[rr] = fmaf(c1, t10, fmaf(c0, dgf, base0));
    L1[rr] = fmaf(c1, t11, fmaf(c0, dgf, base1));
  }
  // A-frags of +2*Ytilde (split) and exact bf16 negation (-2*Ytilde)
  f32x16 y20, y21;
#pragma unroll
  for (int rr = 0; rr < 16; ++rr) { y20[rr] = Q0[rr] + Q0[rr]; y21[rr] = Q1[rr] + Q1[rr]; }
  short8 Y0h[2], Y0l[2], Y1h[2], Y1l[2];
  cmaj_to_bfrag_split(y20, Y0h[0], Y0h[1], Y0l[0], Y0l[1]);
  cmaj_to_bfrag_split(y21, Y1h[0], Y1h[1], Y1l[0], Y1l[1]);
  short8 N0h[2], N0l[2], N1h[2], N1l[2];
#pragma unroll
  for (int t = 0; t < 2; ++t) {
    N0h[t] = neg8(Y0h[t]); N0l[t] = neg8(Y0l[t]);
    N1h[t] = neg8(Y1h[t]); N1l[t] = neg8(Y1l[t]);
  }
  // 6. in-place ping-pong, 2 steps/iter: P = X_even, Q = X_odd (chains interleaved)
#pragma unroll
  for (int k = 2; k < NCHEB; k += 2) {
    // even step k: A = -2Yt; P(X_{k-2}) <- X_k
    {
      short8 B00, B01, B10, B11;
      cmaj_to_bfrag(Q0, B00, B01);
      cmaj_to_bfrag(Q1, B10, B11);
      P0 = MFMA32(N0l[0], B00, P0);
      P1 = MFMA32(N1l[0], B10, P1);
      P0 = MFMA32(N0h[0], B00, P0);
      P1 = MFMA32(N1h[0], B10, P1);
      P0 = MFMA32(N0l[1], B01, P0);
      P1 = MFMA32(N1l[1], B11, P1);
      P0 = MFMA32(N0h[1], B01, P0);
      P1 = MFMA32(N1h[1], B11, P1);
      const float ck = cof[k];
#pragma unroll
      for (int rr = 0; rr < 16; ++rr) {
        L0[rr] = fmaf(ck, P0[rr], L0[rr]);
        L1[rr] = fmaf(ck, P1[rr], L1[rr]);
      }
    }
    // odd step k+1: A = +2Yt; Q(X_{k-1}) <- X_{k+1}
    {
      short8 B00, B01, B10, B11;
      cmaj_to_bfrag(P0, B00, B01);
      cmaj_to_bfrag(P1, B10, B11);
      Q0 = MFMA32(Y0l[0], B00, Q0);
      Q1 = MFMA32(Y1l[0], B10, Q1);
      Q0 = MFMA32(Y0h[0], B00, Q0);
      Q1 = MFMA32(Y1h[0], B10, Q1);
      Q0 = MFMA32(Y0l[1], B01, Q0);
      Q1 = MFMA32(Y1l[1], B11, Q1);
      Q0 = MFMA32(Y0h[1], B01, Q0);
      Q1 = MFMA32(Y1h[1], B11, Q1);
      const float ck = cof[k + 1];
#pragma unroll
      for (int rr = 0; rr < 16; ++rr) {
        L0[rr] = fmaf(ck, Q0[rr], L0[rr]);
        L1[rr] = fmaf(ck, Q1[rr], L1[rr]);
      }
    }
  }
}

// ---------------- 16x16 LDS helpers (kD path, r9-proven, unchanged) ----------------
__device__ __forceinline__ short8 fragr(const u16t (*G)[40], int t, int c15, int g) {
  return *reinterpret_cast<const short8*>(&G[16 * t + c15][8 * g]);
}
__device__ __forceinline__ void stg_single(u16t (*G)[40], int col, int row, f32x4 v) {
  uint2 w; w.x = pack2_rn(v[0], v[1]); w.y = pack2_rn(v[2], v[3]);
  *reinterpret_cast<uint2*>(&G[col][row]) = w;
}
__device__ __forceinline__ void stg_split(u16t (*Gh)[40], u16t (*Gl)[40], int col, int row, f32x4 v) {
  u32t h0, l0, h1, l1;
  split2(v[0], v[1], h0, l0);
  split2(v[2], v[3], h1, l1);
  uint2 hv; hv.x = h0; hv.y = h1;
  uint2 lv; lv.x = l0; lv.y = l1;
  *reinterpret_cast<uint2*>(&Gh[col][row]) = hv;
  *reinterpret_cast<uint2*>(&Gl[col][row]) = lv;
}
__device__ __forceinline__ void load_sym_frags(const float* base, int c15, int g,
                                               short8* Fh, short8* Fl) {
#pragma unroll
  for (int t = 0; t < 2; ++t) {
    const float* sp = base + (16 * t + c15) * 32 + 8 * g;
    short8 hh, ll;
#pragma unroll
    for (int j = 0; j < 8; ++j) {
      u16t h, l;
      splitf(sp[j], h, l);
      hh[j] = (short)h;
      ll[j] = (short)l;
    }
    Fh[t] = hh;
    Fl[t] = ll;
  }
}

// ---------- tiny-kernel helpers (single block, 256 threads; r9-proven) ----------
__device__ __forceinline__ float dotrow36(const float* Arow, const float* v) {
  float s = 0.f;
#pragma unroll
  for (int j = 0; j < 8; ++j) {
    float4 a = *reinterpret_cast<const float4*>(Arow + 4 * j);
    s = fmaf(a.x, v[4 * j + 0], s);
    s = fmaf(a.y, v[4 * j + 1], s);
    s = fmaf(a.z, v[4 * j + 2], s);
    s = fmaf(a.w, v[4 * j + 3], s);
  }
  return s;
}
__device__ void mm64(float (*D)[LDSW], const float (*A)[LDSW], const float (*Bm)[LDSW], int tid) {
  const int h = tid >> 5, c = tid & 31;
  float bcol[32];
#pragma unroll
  for (int k = 0; k < 32; ++k) bcol[k] = Bm[k][c];
  float o[4];
#pragma unroll
  for (int i = 0; i < 4; ++i) o[i] = dotrow36(&A[4 * h + i][0], bcol);
  __syncthreads();
#pragma unroll
  for (int i = 0; i < 4; ++i) D[4 * h + i][c] = o[i];
  __syncthreads();
}
__device__ void ns_sqrt(LdsMat& Y, LdsMat& Z, LdsMat& Ya, LdsMat& Za, LdsMat T, int tid) {
  const int h = tid >> 5, c = tid & 31;
  for (int it = 0; it < NS_ITERS; ++it) {
    mm64(T, Z, Y, tid);
#pragma unroll
    for (int i = 0; i < 4; ++i) {
      int r = 4 * h + i;
      T[r][c] = ((r == c) ? 1.5f : 0.f) - 0.5f * T[r][c];
    }
    __syncthreads();
    mm64(Ya, Y, T, tid);
    mm64(Za, T, Z, tid);
    LdsMat t1 = Y; Y = Ya; Ya = t1;
    LdsMat t2 = Z; Z = Za; Za = t2;
  }
}

// ---------- kernels ----------

extern "C" __global__ void __launch_bounds__(256)
spdbn_kA(const float* __restrict__ x, float* __restrict__ wsf) {
  const int e  = (blockIdx.x & 3) * 256 + threadIdx.x;
  const int bs = blockIdx.x >> 2;
  float acc = 0.f;
  for (int t = 0; t < 64; ++t)
    acc += x[(size_t)(bs + 1024 * t) * 1024 + e];
  atomicAdd(&wsf[OFF_MEAN0 + e], acc);
}

extern "C" __global__ void __launch_bounds__(256)
spdbn_kS1(float* __restrict__ wsf) {
  __shared__ alignas(16) float W0[32][LDSW], W1[32][LDSW], W2[32][LDSW], W3[32][LDSW], W4[32][LDSW];
  const int tid = threadIdx.x, h = tid >> 5, c = tid & 31;
  float sacc = 0.f;
#pragma unroll
  for (int k = 0; k < 32; ++k) sacc += wsf[OFF_MEAN0 + 33 * k];
  const float cN = sacc / (32.f * (float)BATCH);
  const float scaleA = 32.f / sacc;
#pragma unroll
  for (int i = 0; i < 4; ++i) {
    int r = 4 * h + i;
    W1[r][c] = wsf[OFF_MEAN0 + r * 32 + c] * scaleA;
    W2[r][c] = (r == c) ? 1.f : 0.f;
  }
  __syncthreads();
  LdsMat Y = W1, Z = W2, Ya = W0, Za = W4;
  ns_sqrt(Y, Z, Ya, Za, W3, tid);
  const float sq = sqrtf(cN), rs = rsqrtf(cN);
#pragma unroll
  for (int i = 0; i < 4; ++i) {
    int r = 4 * h + i;
    wsf[OFF_INVS0 + r * 32 + c] = Z[r][c] * rs;
    wsf[OFF_S0    + r * 32 + c] = Y[r][c] * sq;
  }
  if (tid < 64) {
    const float PIF = 3.14159265358979f;
    const float th = ((float)tid + 0.5f) * (PIF / 64.f);
    const float t  = 0.5f * (CALPHA + CBETA) + 0.5f * (CBETA - CALPHA) * cosf(th);
    const float fl = logf(t);
    for (int j = 0; j < NCHEB; ++j) {
      float v = fl * cosf((float)j * th) * (2.f / 64.f);
#pragma unroll
      for (int off = 32; off >= 1; off >>= 1) v += __shfl_xor(v, off);
      if (tid == 0) wsf[OFF_CHEB + j] = (j == 0) ? 0.5f * v : v;
    }
  }
}

// Karcher step: accumulate sum_b log(inv_s0 x_b inv_s0)   [register-only, 2-ILP, in-place]
extern "C" __global__ void __launch_bounds__(64, 2)
spdbn_kB(const float* __restrict__ x, float* __restrict__ wsf) {
  const int lane = threadIdx.x, q = lane >> 5, n = lane & 31;
  short8 S_h[2], S_l[2];
  load_sym_frags32(wsf + OFF_INVS0, n, q, S_h, S_l);
  float cof[NCHEB];
#pragma unroll
  for (int k = 0; k < NCHEB; ++k) {
    float sg = ((k >> 1) & 1) ? -1.f : 1.f;   // fold (-1)^floor(k/2) into coeffs
    cof[k] = wsf[OFF_CHEB + k] * sg;
  }
  f32x16 L0, L1;
#pragma unroll
  for (int rr = 0; rr < 16; ++rr) { L0[rr] = 0.f; L1[rr] = 0.f; }
  for (int b = blockIdx.x; b < BATCH / 2; b += gridDim.x)
    whiten_cheb32_x2<true>(x + (size_t)b * 1024, x + (size_t)(b + BATCH / 2) * 1024,
                           S_h, S_l, cof, q, n, L0, L1);
#pragma unroll
  for (int rr = 0; rr < 16; ++rr)
    atomicAdd(&wsf[OFF_LOGAVG + ((rr & 3) + 8 * (rr >> 2) + 4 * q) * 32 + n], L0[rr] + L1[rr]);
}

extern "C" __global__ void __launch_bounds__(256)
spdbn_kS2(float* __restrict__ wsf, const float* __restrict__ shift) {
  __shared__ alignas(16) float W0[32][LDSW], W1[32][LDSW], W2[32][LDSW], W3[32][LDSW], W4[32][LDSW];
  const int tid = threadIdx.x, h = tid >> 5, c = tid & 31;
#pragma unroll
  for (int i = 0; i < 4; ++i) {
    int r = 4 * h + i;
    W0[r][c] = wsf[OFF_LOGAVG + r * 32 + c] * (1.f / (float)BATCH);
    W1[r][c] = (r == c) ? 1.f : 0.f;
  }
  __syncthreads();
  for (int j = EXP_TERMS; j >= 1; --j) {
    mm64(W3, W0, W1, tid);
    const float inv = 1.f / (float)j;
#pragma unroll
    for (int i = 0; i < 4; ++i) {
      int r = 4 * h + i;
      W1[r][c] = ((r == c) ? 1.f : 0.f) + W3[r][c] * inv;
    }
    __syncthreads();
  }
#pragma unroll
  for (int i = 0; i < 4; ++i) { int r = 4 * h + i; W2[r][c] = wsf[OFF_S0 + r * 32 + c]; }
  __syncthreads();
  mm64(W3, W2, W1, tid);
  mm64(W0, W3, W2, tid);
  float tr = 0.f;
#pragma unroll
  for (int k = 0; k < 32; ++k) tr += W0[k][k];
  tr *= (1.f / 32.f);
  const float itr = 1.f / tr;
#pragma unroll
  for (int i = 0; i < 4; ++i) {
    int r = 4 * h + i;
    W1[r][c] = W0[r][c] * itr;
    W2[r][c] = (r == c) ? 1.f : 0.f;
  }
  __syncthreads();
  LdsMat Y = W1, Z = W2, Ya = W0, Za = W4;
  ns_sqrt(Y, Z, Ya, Za, W3, tid);
  const float rs = rsqrtf(tr);
#pragma unroll
  for (int i = 0; i < 4; ++i) { int r = 4 * h + i; wsf[OFF_INVS + r * 32 + c] = Z[r][c] * rs; }
  __syncthreads();
  float tr2 = 0.f;
#pragma unroll
  for (int k = 0; k < 32; ++k) tr2 += shift[33 * k];
  tr2 *= (1.f / 32.f);
  const float itr2 = 1.f / tr2;
#pragma unroll
  for (int i = 0; i < 4; ++i) {
    int r = 4 * h + i;
    W1[r][c] = shift[r * 32 + c] * itr2;
    W2[r][c] = (r == c) ? 1.f : 0.f;
  }
  __syncthreads();
  LdsMat Y2 = W1, Z2 = W2, Ya2 = W0, Za2 = W4;
  ns_sqrt(Y2, Z2, Ya2, Za2, W3, tid);
  const float sq2 = sqrtf(tr2);
#pragma unroll
  for (int i = 0; i < 4; ++i) { int r = 4 * h + i; wsf[OFF_SSQRT + r * 32 + c] = Y2[r][c] * sq2; }
}

// BN whiten: L_b -> d_out (scratch); var += ||L_b||_F^2   [register-only, 2-ILP, in-place]
extern "C" __global__ void __launch_bounds__(64, 2)
spdbn_kC(const float* __restrict__ x, float* __restrict__ wsf, float* __restrict__ outL) {
  const int lane = threadIdx.x, q = lane >> 5, n = lane & 31;
  short8 S_h[2], S_l[2];
  load_sym_frags32(wsf + OFF_INVS, n, q, S_h, S_l);
  float cof[NCHEB];
#pragma unroll
  for (int k = 0; k < NCHEB; ++k) {
    float sg = ((k >> 1) & 1) ? -1.f : 1.f;
    cof[k] = wsf[OFF_CHEB + k] * sg;
  }
  float ss = 0.f;
  f32x16 L0, L1;
  for (int b = blockIdx.x; b < BATCH / 2; b += gridDim.x) {
    whiten_cheb32_x2<false>(x + (size_t)b * 1024, x + (size_t)(b + BATCH / 2) * 1024,
                            S_h, S_l, cof, q, n, L0, L1);
    float* ob0 = outL + (size_t)b * 1024;
    float* ob1 = outL + (size_t)(b + BATCH / 2) * 1024;
#pragma unroll
    for (int rr = 0; rr < 16; ++rr) {
      int off = ((rr & 3) + 8 * (rr >> 2) + 4 * q) * 32 + n;
      float v0 = L0[rr], v1 = L1[rr];
      ob0[off] = v0;
      ob1[off] = v1;
      ss = fmaf(v0, v0, ss);
      ss = fmaf(v1, v1, ss);
    }
  }
#pragma unroll
  for (int off = 32; off >= 1; off >>= 1) ss += __shfl_xor(ss, off);
  if (lane == 0) atomicAdd(&wsf[OFF_VAR], ss);
}

extern "C" __global__ void spdbn_kS3(float* __restrict__ wsf, const float* __restrict__ scale) {
  if (threadIdx.x == 0) {
    float var = wsf[OFF_VAR] * (1.f / (float)BATCH);
    float stdv = sqrtf(var);
    wsf[OFF_P] = scale[0] / (stdv + 1e-5f);
  }
}

// out = s_sqrt * exp(p*L) * s_sqrt  (r9/r11-proven path, unchanged)
extern "C" __global__ void __launch_bounds__(64, 3)
spdbn_kD(float* __restrict__ out, const float* __restrict__ wsf) {
  __shared__ alignas(16) u16t Xh[32][40], Xl[32][40], Bu0[32][40], Bu1[32][40];
  const int lane = threadIdx.x;
  const int g = lane >> 4, c15 = lane & 15;
  short8 Q_h[2], Q_l[2];
  load_sym_frags(wsf + OFF_SSQRT, c15, g, Q_h, Q_l);
  const float p = wsf[OFF_P];
  const f32x4 z4 = {0.f, 0.f, 0.f, 0.f};
  f32x4 dg4;
#pragma unroll
  for (int r = 0; r < 4; ++r) dg4[r] = (4 * g + r == c15) ? 1.f : 0.f;
  uint2 idp; idp.x = pack2_rn(dg4[0], dg4[1]); idp.y = pack2_rn(dg4[2], dg4[3]);
  uint2 zp;  zp.x = 0u; zp.y = 0u;
  for (int b = blockIdx.x; b < BATCH; b += MAIN_BLOCKS) {
    float* ob = out + (size_t)b * 1024;
#pragma unroll
    for (int e = 0; e < 4; ++e) {
      int idx = e * 256 + lane * 4;
      float4 v = *reinterpret_cast<const float4*>(ob + idx);
      int row = idx >> 5, col = idx & 31;
      u32t h0, l0, h1, l1;
      split2(v.x * p, v.y * p, h0, l0);
      split2(v.z * p, v.w * p, h1, l1);
      uint2 hv; hv.x = h0; hv.y = h1;
      uint2 lv; lv.x = l0; lv.y = l1;
      *reinterpret_cast<uint2*>(&Xh[row][col]) = hv;
      *reinterpret_cast<uint2*>(&Xl[row][col]) = lv;
    }
#pragma unroll
    for (int i = 0; i < 2; ++i)
#pragma unroll
      for (int j = 0; j < 2; ++j)
        *reinterpret_cast<uint2*>(&Bu0[16 * j + c15][16 * i + 4 * g]) = (i == j) ? idp : zp;
    __syncthreads();
    short8 Mh[2], Ml[2];
#pragma unroll
    for (int t = 0; t < 2; ++t) { Mh[t] = fragr(Xh, t, c15, g); Ml[t] = fragr(Xl, t, c15, g); }
    f32x4 acc[2][2];
#pragma unroll
    for (int jj = EXP_TERMS; jj >= 2; --jj) {
      const int t = EXP_TERMS - jj;
      const u16t (*R)[40] = (t & 1) ? Bu1 : Bu0;
      u16t (*W)[40]       = (t & 1) ? Bu0 : Bu1;
#pragma unroll
      for (int j = 0; j < 2; ++j) {
        short8 Bh = fragr(R, j, c15, g);
#pragma unroll
        for (int i = 0; i < 2; ++i) {
          f32x4 a = z4;
          a = MFMA16(Ml[i], Bh, a);
          a = MFMA16(Mh[i], Bh, a);
          acc[i][j] = a;
        }
      }
      const float inv = 1.f / (float)jj;
      __syncthreads();
#pragma unroll
      for (int i = 0; i < 2; ++i)
#pragma unroll
        for (int j = 0; j < 2; ++j) {
          f32x4 v;
#pragma unroll
          for (int r = 0; r < 4; ++r)
            v[r] = fmaf(acc[i][j][r], inv, ((16 * i + 4 * g + r) == (16 * j + c15)) ? 1.f : 0.f);
          stg_single(W, 16 * j + c15, 16 * i + 4 * g, v);
        }
      __syncthreads();
    }
#pragma unroll
    for (int j = 0; j < 2; ++j) {
      short8 Bh = fragr(Bu1, j, c15, g);
#pragma unroll
      for (int i = 0; i < 2; ++i) {
        f32x4 a = z4;
        a = MFMA16(Ml[i], Bh, a);
        a = MFMA16(Mh[i], Bh, a);
        acc[i][j] = a;
      }
    }
    __syncthreads();
#pragma unroll
    for (int i = 0; i < 2; ++i)
#pragma unroll
      for (int j = 0; j < 2; ++j) {
        f32x4 v;
#pragma unroll
        for (int r = 0; r < 4; ++r)
          v[r] = acc[i][j][r] + (((16 * i + 4 * g + r) == (16 * j + c15)) ? 1.f : 0.f);
        stg_split(Xh, Xl, 16 * j + c15, 16 * i + 4 * g, v);
      }
    __syncthreads();
    short8 Ph[2], Pl[2];
#pragma unroll
    for (int t = 0; t < 2; ++t) { Ph[t] = fragr(Xh, t, c15, g); Pl[t] = fragr(Xl, t, c15, g); }
#pragma unroll
    for (int i = 0; i < 2; ++i)
#pragma unroll
      for (int j = 0; j < 2; ++j) {
        f32x4 a = z4;
        a = MFMA16(Pl[i], Q_h[j], a);
        a = MFMA16(Ph[i], Q_l[j], a);
        a = MFMA16(Ph[i], Q_h[j], a);
        acc[i][j] = a;
      }
    __syncthreads();
#pragma unroll
    for (int i = 0; i < 2; ++i)
#pragma unroll
      for (int j = 0; j < 2; ++j)
        stg_split(Bu0, Bu1, 16 * j + c15, 16 * i + 4 * g, acc[i][j]);
    __syncthreads();
#pragma unroll
    for (int j = 0; j < 2; ++j) {
      short8 Wh = fragr(Bu0, j, c15, g), Wl = fragr(Bu1, j, c15, g);
#pragma unroll
      for (int i = 0; i < 2; ++i) {
        f32x4 a = z4;
        a = MFMA16(Q_l[i], Wh, a);
        a = MFMA16(Q_h[i], Wl, a);
        a = MFMA16(Q_h[i], Wh, a);
        acc[i][j] = a;
      }
    }
#pragma unroll
    for (int i = 0; i < 2; ++i)
#pragma unroll
      for (int j = 0; j < 2; ++j)
#pragma unroll
        for (int r = 0; r < 4; ++r)
          ob[(16 * i + 4 * g + r) * 32 + 16 * j + c15] = acc[i][j][r];
    __syncthreads();
  }
}

extern "C" void kernel_launch(void* const* d_in, const int* in_sizes, int n_in,
                              void* d_out, int out_size, void* d_ws, size_t ws_size,
                              hipStream_t stream) {
  const float* x     = (const float*)d_in[0];
  const float* shift = (const float*)d_in[1];
  const float* scale = (const float*)d_in[2];
  float* out = (float*)d_out;
  float* wsf = (float*)d_ws;

  size_t zbytes = 32768;
  if (ws_size < zbytes) zbytes = ws_size;
  hipMemsetAsync(d_ws, 0, zbytes, stream);

  hipLaunchKernelGGL(spdbn_kA,  dim3(4096),    dim3(256), 0, stream, x, wsf);
  hipLaunchKernelGGL(spdbn_kS1, dim3(1),       dim3(256), 0, stream, wsf);
  hipLaunchKernelGGL(spdbn_kB,  dim3(GRID_BC), dim3(64),  0, stream, x, wsf);
  hipLaunchKernelGGL(spdbn_kS2, dim3(1),       dim3(256), 0, stream, wsf, shift);
  hipLaunchKernelGGL(spdbn_kC,  dim3(GRID_BC), dim3(64),  0, stream, x, wsf, out);
  hipLaunchKernelGGL(spdbn_kS3, dim3(1),       dim3(64),  0, stream, wsf, scale);
  hipLaunchKernelGGL(spdbn_kD,  dim3(MAIN_BLOCKS), dim3(64), 0, stream, out, wsf);
}